// Round 3
// baseline (740.870 us; speedup 1.0000x reference)
//
#include <hip/hip_runtime.h>

#define NN 100000
#define EE 1000000
#define NFEAT 512
#define NHID 32
#define HEADS 8
#define F1 256               // HEADS*NHID
#define NCLASS 40
#define SLOPE 0.2f
#define NB1 98               // ceil(NN/1024) scan blocks

typedef __bf16 bf16x8 __attribute__((ext_vector_type(8)));
typedef float f32x4 __attribute__((ext_vector_type(4)));

union BF8 { unsigned short s[8]; bf16x8 v; uint4 u; };

__device__ __forceinline__ float bf2f(unsigned short u) {
    return __uint_as_float(((unsigned)u) << 16);
}
__device__ __forceinline__ unsigned short f2bf(float f) {
    unsigned x = __float_as_uint(f);
    unsigned r = (x + 0x7fffu + ((x >> 16) & 1u)) >> 16;
    return (unsigned short)r;
}
__device__ __forceinline__ float lrelu(float x) { return x > 0.f ? x : SLOPE * x; }

// ---------------- edge-index canonicalization (int32 vs int64 layout) --------
__global__ void detect_i64(const int* __restrict__ ei, int* __restrict__ flag) {
    int i = blockIdx.x * 256 + threadIdx.x;
    if (i < 4096) {
        if (ei[2 * i + 1] != 0) atomicOr(flag, 1);   // int64 LE high words are 0
    }
}
// canon + degree count fused (saves one 4MB edge-list pass)
__global__ void canon_edges(const int* __restrict__ ei, const int* __restrict__ flag,
                            int* __restrict__ srcC, int* __restrict__ dstC,
                            int* __restrict__ deg) {
    int e = blockIdx.x * 256 + threadIdx.x;
    if (e >= EE) return;
    int s, d;
    if (*flag) {               // int32 layout
        s = ei[e];
        d = ei[EE + e];
    } else {                   // int64 little-endian layout: read full 8B words
        int2 a = ((const int2*)ei)[e];
        int2 b = ((const int2*)ei)[EE + e];
        s = a.x;
        d = b.x;
    }
    srcC[e] = s;
    dstC[e] = d;
    atomicAdd(deg + d, 1);
}

// ---------------- CSR build: scan, fill ----------------
__global__ void scan1(const int* __restrict__ deg, int* __restrict__ bsum) {
    __shared__ int s[256];
    int b = blockIdx.x, t = threadIdx.x;
    int base = b * 1024 + t * 4, sum = 0;
    #pragma unroll
    for (int j = 0; j < 4; j++) { int i = base + j; sum += (i < NN) ? deg[i] : 0; }
    s[t] = sum; __syncthreads();
    for (int off = 128; off > 0; off >>= 1) {
        if (t < off) s[t] += s[t + off];
        __syncthreads();
    }
    if (t == 0) bsum[b] = s[0];
}
// wave-parallel exclusive scan of NB1=98 block sums
__global__ void scan2(int* __restrict__ bsum, int* __restrict__ row_ptr) {
    int lane = threadIdx.x;                      // single wave of 64
    int v0 = (lane < NB1) ? bsum[lane] : 0;
    int v1 = (64 + lane < NB1) ? bsum[64 + lane] : 0;
    int s0 = v0;
    #pragma unroll
    for (int off = 1; off < 64; off <<= 1) {
        int t = __shfl_up(s0, off);
        if (lane >= off) s0 += t;
    }
    int tot0 = __shfl(s0, 63);
    int s1 = v1;
    #pragma unroll
    for (int off = 1; off < 64; off <<= 1) {
        int t = __shfl_up(s1, off);
        if (lane >= off) s1 += t;
    }
    s1 += tot0;
    if (lane < NB1) bsum[lane] = s0 - v0;        // exclusive
    if (64 + lane < NB1) bsum[64 + lane] = s1 - v1;
    if (lane == 0) row_ptr[NN] = EE;
}
__global__ void scan3(const int* __restrict__ deg, const int* __restrict__ bsum,
                      int* __restrict__ row_ptr, int* __restrict__ pos) {
    __shared__ int ts[256];
    int b = blockIdx.x, t = threadIdx.x;
    int base = b * 1024 + t * 4;
    int v[4], sum = 0;
    #pragma unroll
    for (int j = 0; j < 4; j++) { int i = base + j; v[j] = (i < NN) ? deg[i] : 0; sum += v[j]; }
    ts[t] = sum; __syncthreads();
    for (int off = 1; off < 256; off <<= 1) {
        int add = (t >= off) ? ts[t - off] : 0;
        __syncthreads();
        ts[t] += add;
        __syncthreads();
    }
    int prefix = bsum[b] + ts[t] - sum;          // exclusive prefix for this thread
    #pragma unroll
    for (int j = 0; j < 4; j++) {
        int i = base + j;
        if (i < NN) { row_ptr[i] = prefix; pos[i] = prefix; prefix += v[j]; }
    }
}
__global__ void fill_csr(const int* __restrict__ srcC, const int* __restrict__ dstC,
                         int* __restrict__ pos, int* __restrict__ eadj) {
    int e = blockIdx.x * 256 + threadIdx.x;
    if (e >= EE) return;
    int idx = atomicAdd(pos + dstC[e], 1);
    eadj[idx] = srcC[e];
}

// ---------------- W1 prep: fp32 [512,256] -> bf16 transposed [256,512] -------
__global__ void prep_w1(const float* __restrict__ w1, unsigned short* __restrict__ w1tb) {
    int t = blockIdx.x * 256 + threadIdx.x;
    if (t < NFEAT * F1) {
        int k = t / F1, n = t % F1;
        w1tb[n * NFEAT + k] = f2bf(w1[t]);
    }
}

// ---------------- GEMM1 + fused escore1 ----------------
// hb[N,256] = x[N,512] @ W1 (bf16 MFMA, LDS-staged B), es/ed fused in epilogue.
// LDS B layout is CHUNK-PERMUTED for conflict-free ds_read_b128:
//   16B chunk position p = t*64 + quad*16 + r holds B-row n = t*16+r, k-part quad.
//   Read side: lane (quad,r) at step t reads chunk p = t*64 + lane -> linear in
//   lane, 0 bank conflicts (old layout serialized 4-way within 8-lane groups).
// global_load_lds dest stays linear (base + chunkidx*16); only the SOURCE addr
// is permuted (rule: swizzle via source, dest must be linear).
__device__ __forceinline__ void stage_b(const unsigned short* __restrict__ w1tb,
                                        unsigned short* bs, int kk, int tid) {
    #pragma unroll
    for (int j = 0; j < 4; j++) {
        int p = j * 256 + tid;                   // chunk position 0..1023
        int tq = p >> 6;                         // t  (0..15)
        int qd = (p >> 4) & 3;                   // quad (k-part)
        int rr = p & 15;                         // r
        int n = tq * 16 + rr;                    // B row
        const unsigned short* src = w1tb + n * NFEAT + kk * 32 + qd * 8;
        unsigned short* dst = bs + p * 8;
        __builtin_amdgcn_global_load_lds(
            (const __attribute__((address_space(1))) unsigned int*)src,
            (__attribute__((address_space(3))) unsigned int*)dst, 16, 0, 0);
    }
}

__global__ __launch_bounds__(256) void gemm1_kernel(
    const float* __restrict__ x, const unsigned short* __restrict__ w1tb,
    const float* __restrict__ a_src, const float* __restrict__ a_dst,
    unsigned short* __restrict__ hb, float* __restrict__ es, float* __restrict__ ed) {
    __shared__ unsigned short Bs[2][256 * 32];   // 2 x 16 KB
    __shared__ float As_[F1], Ad_[F1];
    int tid = threadIdx.x;
    As_[tid] = a_src[tid];                       // first barrier covers this
    Ad_[tid] = a_dst[tid];
    int wave = tid >> 6, lane = tid & 63;
    int quad = lane >> 4, r = lane & 15;
    int mBase = blockIdx.x * 64 + wave * 16;
    long arow = mBase + r; if (arow > NN - 1) arow = NN - 1;
    const float* aptr = x + arow * NFEAT + quad * 8;

    // prologue: stage Bs[0] and issue A-loads for kk=0
    stage_b(w1tb, Bs[0], 0, tid);
    float4 fa0 = *(const float4*)(aptr);
    float4 fa1 = *(const float4*)(aptr + 4);

    f32x4 acc[16];
    #pragma unroll
    for (int t = 0; t < 16; t++) acc[t] = {0.f, 0.f, 0.f, 0.f};

    for (int kk = 0; kk < 16; kk++) {
        __syncthreads();                          // drains stage(kk) + fa(kk)
        float4 nf0, nf1;
        if (kk + 1 < 16) {                        // issue next-step loads early:
            stage_b(w1tb, Bs[(kk + 1) & 1], kk + 1, tid);   // B -> other buffer
            nf0 = *(const float4*)(aptr + (kk + 1) * 32);   // A -> regs
            nf1 = *(const float4*)(aptr + (kk + 1) * 32 + 4);
        }
        float fa[8] = {fa0.x, fa0.y, fa0.z, fa0.w, fa1.x, fa1.y, fa1.z, fa1.w};
        BF8 ah;
        #pragma unroll
        for (int j = 0; j < 8; j++) ah.s[j] = f2bf(fa[j]);
        const unsigned short* bsc = Bs[kk & 1];
        #pragma unroll
        for (int t = 0; t < 16; t++) {
            BF8 vb;
            // permuted layout: chunk p = t*64 + quad*16 + r -> shorts offset p*8
            vb.u = *(const uint4*)(bsc + (t * 64 + quad * 16 + r) * 8);
            acc[t] = __builtin_amdgcn_mfma_f32_16x16x32_bf16(ah.v, vb.v, acc[t], 0, 0, 0);
        }
        if (kk + 1 < 16) { fa0 = nf0; fa1 = nf1; }
    }
    // epilogue: store bf16 row + per-head a_src/a_dst partial dots
    #pragma unroll
    for (int i = 0; i < 4; i++) {
        int m = mBase + quad * 4 + i;
        if (m < NN) {
            unsigned short* hp = hb + (long)m * F1 + r;
            #pragma unroll
            for (int t = 0; t < 16; t++) hp[t * 16] = f2bf(acc[t][i]);
        }
        float pv[16];
        #pragma unroll
        for (int k = 0; k < 16; k++) pv[k] = 0.f;
        #pragma unroll
        for (int t = 0; t < 16; t++) {
            float hv = bf2f(f2bf(acc[t][i]));    // same rounded value escore read
            int hd = t >> 1;
            pv[hd]     += hv * As_[t * 16 + r];
            pv[8 + hd] += hv * Ad_[t * 16 + r];
        }
        #pragma unroll
        for (int b = 1; b <= 8; b <<= 1) {
            #pragma unroll
            for (int k = 0; k < 16; k++) pv[k] += __shfl_xor(pv[k], b);
        }
        if (m < NN) {
            float v = pv[0];
            #pragma unroll
            for (int k = 1; k < 16; k++) v = (r == k) ? pv[k] : v;
            int hd = r & 7;
            if (r < 8) es[(long)m * 8 + hd] = v;
            else       ed[(long)m * 8 + hd] = v;
        }
    }
}

// ---------------- layer-1 fused: ONLINE softmax + aggregate + bias + ELU -----
// one wave per dst; 8 edges x 8 heads score lanes; 2-half x 16B gather lanes;
// eadj for the NEXT group prefetched one iteration ahead.
__global__ __launch_bounds__(256) void gat1_fused(
    const int* __restrict__ row_ptr, const int* __restrict__ eadj,
    const float* __restrict__ es, const float* __restrict__ ed,
    const unsigned short* __restrict__ hb, const float* __restrict__ b1,
    float* __restrict__ h1o) {
    int wave = threadIdx.x >> 6, lane = threadIdx.x & 63;
    int d = blockIdx.x * 4 + wave;
    if (d >= NN) return;
    int eslot = lane >> 3, hd8 = lane & 7;
    int half = lane >> 5, sub = lane & 31, hh = sub >> 2;
    float edv = ed[d * 8 + hd8];
    int beg = row_ptr[d], end = row_ptr[d + 1];

    float mself = lrelu(es[d * 8 + hd8] + edv);
    float m = mself;
    float den = (eslot == 0) ? 1.f : 0.f;

    float a0, a1, a2, a3, a4, a5, a6, a7;
    if (half == 0) {                              // self row, weight 1
        uint4 u = ((const uint4*)(hb + (long)d * F1))[sub];
        a0 = bf2f((unsigned short)(u.x & 0xffffu)); a1 = bf2f((unsigned short)(u.x >> 16));
        a2 = bf2f((unsigned short)(u.y & 0xffffu)); a3 = bf2f((unsigned short)(u.y >> 16));
        a4 = bf2f((unsigned short)(u.z & 0xffffu)); a5 = bf2f((unsigned short)(u.z >> 16));
        a6 = bf2f((unsigned short)(u.w & 0xffffu)); a7 = bf2f((unsigned short)(u.w >> 16));
    } else {
        a0 = a1 = a2 = a3 = a4 = a5 = a6 = a7 = 0.f;
    }

    int sPre = (beg + eslot < end) ? eadj[beg + eslot] : 0;
    for (int i = beg; i < end; i += 8) {
        int idx = i + eslot;
        int s = sPre;
        if (i + 8 < end) {                        // prefetch next group's index
            int nidx = idx + 8;
            sPre = (nidx < end) ? eadj[nidx] : 0;
        }
        float el = lrelu(es[s * 8 + hd8] + edv);
        if (idx >= end) el = -1e30f;
        float gm = el;
        gm = fmaxf(gm, __shfl_xor(gm, 8));
        gm = fmaxf(gm, __shfl_xor(gm, 16));
        gm = fmaxf(gm, __shfl_xor(gm, 32));
        float mn = fmaxf(m, gm);
        float rsc = __expf(m - mn);               // == 1.0 exactly when no growth
        m = mn;
        den *= rsc;
        float wj = (idx < end) ? __expf(el - m) : 0.f;
        den += wj;
        float ro = __shfl(rsc, hh);               // rescale factor for col-head hh
        a0 *= ro; a1 *= ro; a2 *= ro; a3 *= ro;
        a4 *= ro; a5 *= ro; a6 *= ro; a7 *= ro;

        int cnt = min(8, end - i);
        #pragma unroll
        for (int jj = 0; jj < 4; jj++) {
            int e = jj * 2 + half;
            float w = __shfl(wj, e * 8 + hh);
            int sj = __shfl(s, e * 8);
            if (e < cnt) {
                uint4 u = ((const uint4*)(hb + (long)sj * F1))[sub];
                a0 += w * bf2f((unsigned short)(u.x & 0xffffu));
                a1 += w * bf2f((unsigned short)(u.x >> 16));
                a2 += w * bf2f((unsigned short)(u.y & 0xffffu));
                a3 += w * bf2f((unsigned short)(u.y >> 16));
                a4 += w * bf2f((unsigned short)(u.z & 0xffffu));
                a5 += w * bf2f((unsigned short)(u.z >> 16));
                a6 += w * bf2f((unsigned short)(u.w & 0xffffu));
                a7 += w * bf2f((unsigned short)(u.w >> 16));
            }
        }
    }
    den += __shfl_xor(den, 8);
    den += __shfl_xor(den, 16);
    den += __shfl_xor(den, 32);
    float deno = __shfl(den, hh);

    a0 += __shfl_xor(a0, 32); a1 += __shfl_xor(a1, 32);
    a2 += __shfl_xor(a2, 32); a3 += __shfl_xor(a3, 32);
    a4 += __shfl_xor(a4, 32); a5 += __shfl_xor(a5, 32);
    a6 += __shfl_xor(a6, 32); a7 += __shfl_xor(a7, 32);

    if (half == 0) {
        float inv = 1.f / deno;
        float4 blo = ((const float4*)b1)[sub * 2];
        float4 bhi = ((const float4*)b1)[sub * 2 + 1];
        float r0 = a0 * inv + blo.x, r1 = a1 * inv + blo.y;
        float r2 = a2 * inv + blo.z, r3 = a3 * inv + blo.w;
        float r4 = a4 * inv + bhi.x, r5 = a5 * inv + bhi.y;
        float r6 = a6 * inv + bhi.z, r7 = a7 * inv + bhi.w;
        r0 = r0 > 0.f ? r0 : expm1f(r0); r1 = r1 > 0.f ? r1 : expm1f(r1);
        r2 = r2 > 0.f ? r2 : expm1f(r2); r3 = r3 > 0.f ? r3 : expm1f(r3);
        r4 = r4 > 0.f ? r4 : expm1f(r4); r5 = r5 > 0.f ? r5 : expm1f(r5);
        r6 = r6 > 0.f ? r6 : expm1f(r6); r7 = r7 > 0.f ? r7 : expm1f(r7);
        float4 o0 = {r0, r1, r2, r3}, o1 = {r4, r5, r6, r7};
        ((float4*)(h1o + (long)d * F1))[sub * 2] = o0;
        ((float4*)(h1o + (long)d * F1))[sub * 2 + 1] = o1;
    }
}

// ---------------- GEMM2: h2[N,40] = h1[N,256] @ W2 (fp32, W2 in LDS) ----------
__global__ __launch_bounds__(256) void gemm2_kernel(const float* __restrict__ h1,
                                                    const float* __restrict__ w2,
                                                    float* __restrict__ h2) {
    __shared__ float4 Ws[F1 * 10];
    for (int i = threadIdx.x; i < F1 * 10; i += 256) Ws[i] = ((const float4*)w2)[i];
    __syncthreads();
    long t = (long)blockIdx.x * 256 + threadIdx.x;
    if (t >= (long)NN * 10) return;
    int n = (int)(t / 10);
    int j = (int)(t - (long)n * 10);
    const float4* hp = (const float4*)(h1 + (long)n * F1);
    float4 a = {0.f, 0.f, 0.f, 0.f};
    #pragma unroll 8
    for (int k4 = 0; k4 < 64; k4++) {
        float4 hv = hp[k4];
        float4 w0 = Ws[(k4 * 4 + 0) * 10 + j];
        float4 w1v = Ws[(k4 * 4 + 1) * 10 + j];
        float4 w2v = Ws[(k4 * 4 + 2) * 10 + j];
        float4 w3v = Ws[(k4 * 4 + 3) * 10 + j];
        a.x += hv.x * w0.x + hv.y * w1v.x + hv.z * w2v.x + hv.w * w3v.x;
        a.y += hv.x * w0.y + hv.y * w1v.y + hv.z * w2v.y + hv.w * w3v.y;
        a.z += hv.x * w0.z + hv.y * w1v.z + hv.z * w2v.z + hv.w * w3v.z;
        a.w += hv.x * w0.w + hv.y * w1v.w + hv.z * w2v.w + hv.w * w3v.w;
    }
    ((float4*)(h2 + (long)n * NCLASS))[j] = a;
}

// ---------------- e_src/e_dst layer2 ----------------
__global__ void escore2_kernel(const float* __restrict__ h2,
                               const float* __restrict__ a_src2,
                               const float* __restrict__ a_dst2,
                               float* __restrict__ e2s, float* __restrict__ e2d) {
    __shared__ float As[NCLASS], Ad[NCLASS];
    if (threadIdx.x < NCLASS) {
        As[threadIdx.x] = a_src2[threadIdx.x];
        Ad[threadIdx.x] = a_dst2[threadIdx.x];
    }
    __syncthreads();
    int n = blockIdx.x * 256 + threadIdx.x;
    if (n >= NN) return;
    const float* hp = h2 + (long)n * NCLASS;
    float s = 0.f, d = 0.f;
    #pragma unroll
    for (int c = 0; c < NCLASS; c++) {
        float v = hp[c];
        s += v * As[c];
        d += v * Ad[c];
    }
    e2s[n] = s; e2d[n] = d;
}

// ---------------- layer-2 fused: ONLINE softmax-agg + bias + log_softmax -----
__global__ __launch_bounds__(256) void gat2_logsm(
    const int* __restrict__ row_ptr, const int* __restrict__ eadj,
    const float* __restrict__ e2s, const float* __restrict__ e2d,
    const float* __restrict__ h2, const float* __restrict__ b2,
    float* __restrict__ out0) {
    int wave = threadIdx.x >> 6, lane = threadIdx.x & 63;
    int d = blockIdx.x * 4 + wave;
    if (d >= NN) return;
    int eslot = lane >> 3, c8 = lane & 7;
    float edv = e2d[d];
    int beg = row_ptr[d], end = row_ptr[d + 1];

    float mself = lrelu(e2s[d] + edv);
    float m = mself;
    float den = (eslot == 0) ? 1.f : 0.f;
    float acc[5];
    {
        const float* hp = h2 + (long)d * NCLASS + c8 * 5;
        #pragma unroll
        for (int k = 0; k < 5; k++) acc[k] = (eslot == 0) ? hp[k] : 0.f;
    }

    int sPre = (beg + eslot < end) ? eadj[beg + eslot] : 0;
    for (int i = beg; i < end; i += 8) {
        int idx = i + eslot;
        int s = sPre;
        if (i + 8 < end) {                        // prefetch next group's index
            int nidx = idx + 8;
            sPre = (nidx < end) ? eadj[nidx] : 0;
        }
        float el = lrelu(e2s[s] + edv);
        if (idx >= end) el = -1e30f;
        float gm = el;
        gm = fmaxf(gm, __shfl_xor(gm, 8));
        gm = fmaxf(gm, __shfl_xor(gm, 16));
        gm = fmaxf(gm, __shfl_xor(gm, 32));
        float mn = fmaxf(m, gm);
        float rsc = __expf(m - mn);        // 1.0 when no growth
        m = mn;
        den *= rsc;
        #pragma unroll
        for (int k = 0; k < 5; k++) acc[k] *= rsc;
        float wj = (idx < end) ? __expf(el - m) : 0.f;
        den += wj;
        if (idx < end) {
            const float* hp = h2 + (long)s * NCLASS + c8 * 5;
            #pragma unroll
            for (int k = 0; k < 5; k++) acc[k] += wj * hp[k];
        }
    }
    #pragma unroll
    for (int off = 8; off <= 32; off <<= 1) {
        den += __shfl_xor(den, off);
        #pragma unroll
        for (int k = 0; k < 5; k++) acc[k] += __shfl_xor(acc[k], off);
    }
    float inv = 1.f / den;
    float v[5];
    float mx = -1e30f;
    #pragma unroll
    for (int k = 0; k < 5; k++) {
        v[k] = acc[k] * inv + b2[c8 * 5 + k];
        mx = fmaxf(mx, v[k]);
    }
    #pragma unroll
    for (int off = 1; off <= 4; off <<= 1) mx = fmaxf(mx, __shfl_xor(mx, off));
    float sm = 0.f;
    #pragma unroll
    for (int k = 0; k < 5; k++) sm += __expf(v[k] - mx);
    #pragma unroll
    for (int off = 1; off <= 4; off <<= 1) sm += __shfl_xor(sm, off);
    float ls = mx + logf(sm);
    if (eslot == 0) {
        float* op = out0 + (long)d * NCLASS + c8 * 5;
        #pragma unroll
        for (int k = 0; k < 5; k++) op[k] = v[k] - ls;
    }
}

extern "C" void kernel_launch(void* const* d_in, const int* in_sizes, int n_in,
                              void* d_out, int out_size, void* d_ws, size_t ws_size,
                              hipStream_t stream) {
    const float* x   = (const float*)d_in[0];
    const int* ei    = (const int*)d_in[1];
    const float* W1  = (const float*)d_in[2];
    const float* as1 = (const float*)d_in[3];
    const float* ad1 = (const float*)d_in[4];
    const float* b1  = (const float*)d_in[5];
    const float* W2  = (const float*)d_in[6];
    const float* as2 = (const float*)d_in[7];
    const float* ad2 = (const float*)d_in[8];
    const float* b2  = (const float*)d_in[9];

    float* out0 = (float*)d_out;                   // [N,40] log_softmax
    float* h1o  = out0 + (long)NN * NCLASS;        // [N,256] h1 (fp32)

    // workspace layout
    unsigned short* hb = (unsigned short*)d_ws;               // N*F1 bf16 (51.2 MB)
    unsigned short* w1tb = hb + (long)NN * F1;                // 256*512 bf16
    float* es1  = (float*)(w1tb + F1 * NFEAT);                // N*8
    float* ed1  = es1 + NN * HEADS;
    float* e2s  = ed1 + NN * HEADS;                           // N
    float* e2d  = e2s + NN;
    int* srcC   = (int*)(e2d + NN);                           // E
    int* dstC   = srcC + EE;                                  // E
    int* eadj   = dstC + EE;                                  // E
    int* deg    = eadj + EE;                                  // N
    int* row_ptr= deg + NN;                                   // N+1
    int* pos    = row_ptr + NN + 1;                           // N
    int* bsum   = pos + NN;                                   // NB1
    int* flag   = bsum + NB1;                                 // 1
    float* h2   = (float*)d_ws;                               // alias: N*40 (hb dead after gat1)

    hipMemsetAsync(flag, 0, 4, stream);
    hipMemsetAsync(deg, 0, (size_t)NN * 4, stream);

    // edge canonicalization + CSR build (canon fused with degree count)
    detect_i64<<<16, 256, 0, stream>>>(ei, flag);
    canon_edges<<<(EE + 255) / 256, 256, 0, stream>>>(ei, flag, srcC, dstC, deg);
    scan1<<<NB1, 256, 0, stream>>>(deg, bsum);
    scan2<<<1, 64, 0, stream>>>(bsum, row_ptr);
    scan3<<<NB1, 256, 0, stream>>>(deg, bsum, row_ptr, pos);
    fill_csr<<<(EE + 255) / 256, 256, 0, stream>>>(srcC, dstC, pos, eadj);

    // layer 1 (escore1 fused into gemm1 epilogue)
    prep_w1<<<(NFEAT * F1 + 255) / 256, 256, 0, stream>>>(W1, w1tb);
    gemm1_kernel<<<(NN + 63) / 64, 256, 0, stream>>>(x, w1tb, as1, ad1, hb, es1, ed1);
    gat1_fused<<<(NN + 3) / 4, 256, 0, stream>>>(row_ptr, eadj, es1, ed1, hb, b1, h1o);

    // layer 2
    gemm2_kernel<<<(int)(((long)NN * 10 + 255) / 256), 256, 0, stream>>>(h1o, W2, h2);
    escore2_kernel<<<(NN + 255) / 256, 256, 0, stream>>>(h2, as2, ad2, e2s, e2d);
    gat2_logsm<<<(NN + 3) / 4, 256, 0, stream>>>(row_ptr, eadj, e2s, e2d, h2, b2, out0);
}

// Round 5
// 709.904 us; speedup vs baseline: 1.0436x; 1.0436x over previous
//
#include <hip/hip_runtime.h>

#define NN 100000
#define EE 1000000
#define NFEAT 512
#define NHID 32
#define HEADS 8
#define F1 256               // HEADS*NHID
#define NCLASS 40
#define SLOPE 0.2f
#define NB1 98               // ceil(NN/1024) scan blocks

typedef __bf16 bf16x8 __attribute__((ext_vector_type(8)));
typedef float f32x4 __attribute__((ext_vector_type(4)));

union BF8 { unsigned short s[8]; bf16x8 v; uint4 u; };

__device__ __forceinline__ float bf2f(unsigned short u) {
    return __uint_as_float(((unsigned)u) << 16);
}
__device__ __forceinline__ unsigned short f2bf(float f) {
    unsigned x = __float_as_uint(f);
    unsigned r = (x + 0x7fffu + ((x >> 16) & 1u)) >> 16;
    return (unsigned short)r;
}
__device__ __forceinline__ float lrelu(float x) { return x > 0.f ? x : SLOPE * x; }

// ---------------- edge-index canonicalization (int32 vs int64 layout) --------
__global__ void detect_i64(const int* __restrict__ ei, int* __restrict__ flag) {
    int i = blockIdx.x * 256 + threadIdx.x;
    if (i < 4096) {
        if (ei[2 * i + 1] != 0) atomicOr(flag, 1);   // int64 LE high words are 0
    }
}
// canon + degree count fused (saves one 4MB edge-list pass)
__global__ void canon_edges(const int* __restrict__ ei, const int* __restrict__ flag,
                            int* __restrict__ srcC, int* __restrict__ dstC,
                            int* __restrict__ deg) {
    int e = blockIdx.x * 256 + threadIdx.x;
    if (e >= EE) return;
    int s, d;
    if (*flag) {               // int32 layout
        s = ei[e];
        d = ei[EE + e];
    } else {                   // int64 little-endian layout: read full 8B words
        int2 a = ((const int2*)ei)[e];
        int2 b = ((const int2*)ei)[EE + e];
        s = a.x;
        d = b.x;
    }
    srcC[e] = s;
    dstC[e] = d;
    atomicAdd(deg + d, 1);
}

// ---------------- CSR build: scan, fill ----------------
__global__ void scan1(const int* __restrict__ deg, int* __restrict__ bsum) {
    __shared__ int s[256];
    int b = blockIdx.x, t = threadIdx.x;
    int base = b * 1024 + t * 4, sum = 0;
    #pragma unroll
    for (int j = 0; j < 4; j++) { int i = base + j; sum += (i < NN) ? deg[i] : 0; }
    s[t] = sum; __syncthreads();
    for (int off = 128; off > 0; off >>= 1) {
        if (t < off) s[t] += s[t + off];
        __syncthreads();
    }
    if (t == 0) bsum[b] = s[0];
}
// wave-parallel exclusive scan of NB1=98 block sums
__global__ void scan2(int* __restrict__ bsum, int* __restrict__ row_ptr) {
    int lane = threadIdx.x;                      // single wave of 64
    int v0 = (lane < NB1) ? bsum[lane] : 0;
    int v1 = (64 + lane < NB1) ? bsum[64 + lane] : 0;
    int s0 = v0;
    #pragma unroll
    for (int off = 1; off < 64; off <<= 1) {
        int t = __shfl_up(s0, off);
        if (lane >= off) s0 += t;
    }
    int tot0 = __shfl(s0, 63);
    int s1 = v1;
    #pragma unroll
    for (int off = 1; off < 64; off <<= 1) {
        int t = __shfl_up(s1, off);
        if (lane >= off) s1 += t;
    }
    s1 += tot0;
    if (lane < NB1) bsum[lane] = s0 - v0;        // exclusive
    if (64 + lane < NB1) bsum[64 + lane] = s1 - v1;
    if (lane == 0) row_ptr[NN] = EE;
}
__global__ void scan3(const int* __restrict__ deg, const int* __restrict__ bsum,
                      int* __restrict__ row_ptr, int* __restrict__ pos) {
    __shared__ int ts[256];
    int b = blockIdx.x, t = threadIdx.x;
    int base = b * 1024 + t * 4;
    int v[4], sum = 0;
    #pragma unroll
    for (int j = 0; j < 4; j++) { int i = base + j; v[j] = (i < NN) ? deg[i] : 0; sum += v[j]; }
    ts[t] = sum; __syncthreads();
    for (int off = 1; off < 256; off <<= 1) {
        int add = (t >= off) ? ts[t - off] : 0;
        __syncthreads();
        ts[t] += add;
        __syncthreads();
    }
    int prefix = bsum[b] + ts[t] - sum;          // exclusive prefix for this thread
    #pragma unroll
    for (int j = 0; j < 4; j++) {
        int i = base + j;
        if (i < NN) { row_ptr[i] = prefix; pos[i] = prefix; prefix += v[j]; }
    }
}
__global__ void fill_csr(const int* __restrict__ srcC, const int* __restrict__ dstC,
                         int* __restrict__ pos, int* __restrict__ eadj) {
    int e = blockIdx.x * 256 + threadIdx.x;
    if (e >= EE) return;
    int idx = atomicAdd(pos + dstC[e], 1);
    eadj[idx] = srcC[e];
}

// ---------------- W1 prep: fp32 [512,256] -> PACKED bf16 staging order -------
// w1p element o = ((kk*16 + t)*4 + quad)*128 + r*8 + u  holds
// W1[kk*32 + quad*8 + u][t*16 + r]  (bf16).  This makes the gemm1 staging
// source LINEAR: lds chunk p of k-step kk reads w1p + (kk*1024+p)*8 -- perfect
// per-wave coalescing -- while the LDS layout is linear-in-lane on the read
// side (0 bank conflicts).  (R3's permuted-source variant scattered lanes at
// 1024B stride -> 4x memory requests on the staging path -> 46us regression.)
__global__ void prep_w1(const float* __restrict__ w1, unsigned short* __restrict__ w1p) {
    int o = blockIdx.x * 256 + threadIdx.x;
    if (o < NFEAT * F1) {
        int u = o & 7;
        int r = (o >> 3) & 15;
        int quad = (o >> 7) & 3;
        int t = (o >> 9) & 15;
        int kk = o >> 13;
        int k = kk * 32 + quad * 8 + u;
        int n = t * 16 + r;
        w1p[o] = f2bf(w1[k * F1 + n]);
    }
}

// ---------------- GEMM1 + fused escore1 ----------------
// hb[N,256] = x[N,512] @ W1 (bf16 MFMA, LDS-staged B), es/ed fused in epilogue.
// Staging: chunk p (0..1023) of k-step kk comes from w1p+(kk*1024+p)*8, 16B per
// lane, consecutive lanes -> consecutive chunks (coalesced); LDS dest linear.
// Read: lane (quad,r) at step t reads chunk t*64 + quad*16 + r = t*64 + lane
// -> linear in lane, conflict-free.  A-row loads software-pipelined one k-step
// ahead (issued with the stage, drained by the next barrier).
__device__ __forceinline__ void stage_b(const unsigned short* __restrict__ w1p,
                                        unsigned short* bs, int kk, int tid) {
    #pragma unroll
    for (int j = 0; j < 4; j++) {
        int p = j * 256 + tid;                   // chunk position 0..1023
        const unsigned short* src = w1p + (kk * 1024 + p) * 8;
        unsigned short* dst = bs + p * 8;
        __builtin_amdgcn_global_load_lds(
            (const __attribute__((address_space(1))) unsigned int*)src,
            (__attribute__((address_space(3))) unsigned int*)dst, 16, 0, 0);
    }
}

__global__ __launch_bounds__(256) void gemm1_kernel(
    const float* __restrict__ x, const unsigned short* __restrict__ w1p,
    const float* __restrict__ a_src, const float* __restrict__ a_dst,
    unsigned short* __restrict__ hb, float* __restrict__ es, float* __restrict__ ed) {
    __shared__ unsigned short Bs[2][256 * 32];   // 2 x 16 KB
    __shared__ float As_[F1], Ad_[F1];
    int tid = threadIdx.x;
    As_[tid] = a_src[tid];                       // first barrier covers this
    Ad_[tid] = a_dst[tid];
    int wave = tid >> 6, lane = tid & 63;
    int quad = lane >> 4, r = lane & 15;
    int mBase = blockIdx.x * 64 + wave * 16;
    long arow = mBase + r; if (arow > NN - 1) arow = NN - 1;
    const float* aptr = x + arow * NFEAT + quad * 8;

    // prologue: stage Bs[0] and issue A-loads for kk=0
    stage_b(w1p, Bs[0], 0, tid);
    float4 fa0 = *(const float4*)(aptr);
    float4 fa1 = *(const float4*)(aptr + 4);

    f32x4 acc[16];
    #pragma unroll
    for (int t = 0; t < 16; t++) acc[t] = {0.f, 0.f, 0.f, 0.f};

    for (int kk = 0; kk < 16; kk++) {
        __syncthreads();                          // drains stage(kk) + fa(kk)
        float4 nf0, nf1;
        if (kk + 1 < 16) {                        // issue next-step loads early:
            stage_b(w1p, Bs[(kk + 1) & 1], kk + 1, tid);    // B -> other buffer
            nf0 = *(const float4*)(aptr + (kk + 1) * 32);   // A -> regs
            nf1 = *(const float4*)(aptr + (kk + 1) * 32 + 4);
        }
        float fa[8] = {fa0.x, fa0.y, fa0.z, fa0.w, fa1.x, fa1.y, fa1.z, fa1.w};
        BF8 ah;
        #pragma unroll
        for (int j = 0; j < 8; j++) ah.s[j] = f2bf(fa[j]);
        const unsigned short* bsc = Bs[kk & 1];
        #pragma unroll
        for (int t = 0; t < 16; t++) {
            BF8 vb;
            // linear layout: chunk p = t*64 + lane -> shorts offset p*8
            vb.u = *(const uint4*)(bsc + (t * 64 + quad * 16 + r) * 8);
            acc[t] = __builtin_amdgcn_mfma_f32_16x16x32_bf16(ah.v, vb.v, acc[t], 0, 0, 0);
        }
        if (kk + 1 < 16) { fa0 = nf0; fa1 = nf1; }
    }
    // epilogue: store bf16 row + per-head a_src/a_dst partial dots
    #pragma unroll
    for (int i = 0; i < 4; i++) {
        int m = mBase + quad * 4 + i;
        if (m < NN) {
            unsigned short* hp = hb + (long)m * F1 + r;
            #pragma unroll
            for (int t = 0; t < 16; t++) hp[t * 16] = f2bf(acc[t][i]);
        }
        float pv[16];
        #pragma unroll
        for (int k = 0; k < 16; k++) pv[k] = 0.f;
        #pragma unroll
        for (int t = 0; t < 16; t++) {
            float hv = bf2f(f2bf(acc[t][i]));    // same rounded value escore read
            int hd = t >> 1;
            pv[hd]     += hv * As_[t * 16 + r];
            pv[8 + hd] += hv * Ad_[t * 16 + r];
        }
        #pragma unroll
        for (int b = 1; b <= 8; b <<= 1) {
            #pragma unroll
            for (int k = 0; k < 16; k++) pv[k] += __shfl_xor(pv[k], b);
        }
        if (m < NN) {
            float v = pv[0];
            #pragma unroll
            for (int k = 1; k < 16; k++) v = (r == k) ? pv[k] : v;
            int hd = r & 7;
            if (r < 8) es[(long)m * 8 + hd] = v;
            else       ed[(long)m * 8 + hd] = v;
        }
    }
}

// ---------------- layer-1 fused: ONLINE softmax + aggregate + bias + ELU -----
// one wave per dst; 8 edges x 8 heads score lanes; 2-half x 16B gather lanes;
// eadj for the NEXT group prefetched one iteration ahead.
__global__ __launch_bounds__(256) void gat1_fused(
    const int* __restrict__ row_ptr, const int* __restrict__ eadj,
    const float* __restrict__ es, const float* __restrict__ ed,
    const unsigned short* __restrict__ hb, const float* __restrict__ b1,
    float* __restrict__ h1o) {
    int wave = threadIdx.x >> 6, lane = threadIdx.x & 63;
    int d = blockIdx.x * 4 + wave;
    if (d >= NN) return;
    int eslot = lane >> 3, hd8 = lane & 7;
    int half = lane >> 5, sub = lane & 31, hh = sub >> 2;
    float edv = ed[d * 8 + hd8];
    int beg = row_ptr[d], end = row_ptr[d + 1];

    float mself = lrelu(es[d * 8 + hd8] + edv);
    float m = mself;
    float den = (eslot == 0) ? 1.f : 0.f;

    float a0, a1, a2, a3, a4, a5, a6, a7;
    if (half == 0) {                              // self row, weight 1
        uint4 u = ((const uint4*)(hb + (long)d * F1))[sub];
        a0 = bf2f((unsigned short)(u.x & 0xffffu)); a1 = bf2f((unsigned short)(u.x >> 16));
        a2 = bf2f((unsigned short)(u.y & 0xffffu)); a3 = bf2f((unsigned short)(u.y >> 16));
        a4 = bf2f((unsigned short)(u.z & 0xffffu)); a5 = bf2f((unsigned short)(u.z >> 16));
        a6 = bf2f((unsigned short)(u.w & 0xffffu)); a7 = bf2f((unsigned short)(u.w >> 16));
    } else {
        a0 = a1 = a2 = a3 = a4 = a5 = a6 = a7 = 0.f;
    }

    int sPre = (beg + eslot < end) ? eadj[beg + eslot] : 0;
    for (int i = beg; i < end; i += 8) {
        int idx = i + eslot;
        int s = sPre;
        if (i + 8 < end) {                        // prefetch next group's index
            int nidx = idx + 8;
            sPre = (nidx < end) ? eadj[nidx] : 0;
        }
        float el = lrelu(es[s * 8 + hd8] + edv);
        if (idx >= end) el = -1e30f;
        float gm = el;
        gm = fmaxf(gm, __shfl_xor(gm, 8));
        gm = fmaxf(gm, __shfl_xor(gm, 16));
        gm = fmaxf(gm, __shfl_xor(gm, 32));
        float mn = fmaxf(m, gm);
        float rsc = __expf(m - mn);               // == 1.0 exactly when no growth
        m = mn;
        den *= rsc;
        float wj = (idx < end) ? __expf(el - m) : 0.f;
        den += wj;
        float ro = __shfl(rsc, hh);               // rescale factor for col-head hh
        a0 *= ro; a1 *= ro; a2 *= ro; a3 *= ro;
        a4 *= ro; a5 *= ro; a6 *= ro; a7 *= ro;

        int cnt = min(8, end - i);
        #pragma unroll
        for (int jj = 0; jj < 4; jj++) {
            int e = jj * 2 + half;
            float w = __shfl(wj, e * 8 + hh);
            int sj = __shfl(s, e * 8);
            if (e < cnt) {
                uint4 u = ((const uint4*)(hb + (long)sj * F1))[sub];
                a0 += w * bf2f((unsigned short)(u.x & 0xffffu));
                a1 += w * bf2f((unsigned short)(u.x >> 16));
                a2 += w * bf2f((unsigned short)(u.y & 0xffffu));
                a3 += w * bf2f((unsigned short)(u.y >> 16));
                a4 += w * bf2f((unsigned short)(u.z & 0xffffu));
                a5 += w * bf2f((unsigned short)(u.z >> 16));
                a6 += w * bf2f((unsigned short)(u.w & 0xffffu));
                a7 += w * bf2f((unsigned short)(u.w >> 16));
            }
        }
    }
    den += __shfl_xor(den, 8);
    den += __shfl_xor(den, 16);
    den += __shfl_xor(den, 32);
    float deno = __shfl(den, hh);

    a0 += __shfl_xor(a0, 32); a1 += __shfl_xor(a1, 32);
    a2 += __shfl_xor(a2, 32); a3 += __shfl_xor(a3, 32);
    a4 += __shfl_xor(a4, 32); a5 += __shfl_xor(a5, 32);
    a6 += __shfl_xor(a6, 32); a7 += __shfl_xor(a7, 32);

    if (half == 0) {
        float inv = 1.f / deno;
        float4 blo = ((const float4*)b1)[sub * 2];
        float4 bhi = ((const float4*)b1)[sub * 2 + 1];
        float r0 = a0 * inv + blo.x, r1 = a1 * inv + blo.y;
        float r2 = a2 * inv + blo.z, r3 = a3 * inv + blo.w;
        float r4 = a4 * inv + bhi.x, r5 = a5 * inv + bhi.y;
        float r6 = a6 * inv + bhi.z, r7 = a7 * inv + bhi.w;
        r0 = r0 > 0.f ? r0 : expm1f(r0); r1 = r1 > 0.f ? r1 : expm1f(r1);
        r2 = r2 > 0.f ? r2 : expm1f(r2); r3 = r3 > 0.f ? r3 : expm1f(r3);
        r4 = r4 > 0.f ? r4 : expm1f(r4); r5 = r5 > 0.f ? r5 : expm1f(r5);
        r6 = r6 > 0.f ? r6 : expm1f(r6); r7 = r7 > 0.f ? r7 : expm1f(r7);
        float4 o0 = {r0, r1, r2, r3}, o1 = {r4, r5, r6, r7};
        ((float4*)(h1o + (long)d * F1))[sub * 2] = o0;
        ((float4*)(h1o + (long)d * F1))[sub * 2 + 1] = o1;
    }
}

// ---------------- GEMM2: h2[N,40] = h1[N,256] @ W2 (fp32, W2 in LDS) ----------
__global__ __launch_bounds__(256) void gemm2_kernel(const float* __restrict__ h1,
                                                    const float* __restrict__ w2,
                                                    float* __restrict__ h2) {
    __shared__ float4 Ws[F1 * 10];
    for (int i = threadIdx.x; i < F1 * 10; i += 256) Ws[i] = ((const float4*)w2)[i];
    __syncthreads();
    long t = (long)blockIdx.x * 256 + threadIdx.x;
    if (t >= (long)NN * 10) return;
    int n = (int)(t / 10);
    int j = (int)(t - (long)n * 10);
    const float4* hp = (const float4*)(h1 + (long)n * F1);
    float4 a = {0.f, 0.f, 0.f, 0.f};
    #pragma unroll 8
    for (int k4 = 0; k4 < 64; k4++) {
        float4 hv = hp[k4];
        float4 w0 = Ws[(k4 * 4 + 0) * 10 + j];
        float4 w1v = Ws[(k4 * 4 + 1) * 10 + j];
        float4 w2v = Ws[(k4 * 4 + 2) * 10 + j];
        float4 w3v = Ws[(k4 * 4 + 3) * 10 + j];
        a.x += hv.x * w0.x + hv.y * w1v.x + hv.z * w2v.x + hv.w * w3v.x;
        a.y += hv.x * w0.y + hv.y * w1v.y + hv.z * w2v.y + hv.w * w3v.y;
        a.z += hv.x * w0.z + hv.y * w1v.z + hv.z * w2v.z + hv.w * w3v.z;
        a.w += hv.x * w0.w + hv.y * w1v.w + hv.z * w2v.w + hv.w * w3v.w;
    }
    ((float4*)(h2 + (long)n * NCLASS))[j] = a;
}

// ---------------- e_src/e_dst layer2 ----------------
__global__ void escore2_kernel(const float* __restrict__ h2,
                               const float* __restrict__ a_src2,
                               const float* __restrict__ a_dst2,
                               float* __restrict__ e2s, float* __restrict__ e2d) {
    __shared__ float As[NCLASS], Ad[NCLASS];
    if (threadIdx.x < NCLASS) {
        As[threadIdx.x] = a_src2[threadIdx.x];
        Ad[threadIdx.x] = a_dst2[threadIdx.x];
    }
    __syncthreads();
    int n = blockIdx.x * 256 + threadIdx.x;
    if (n >= NN) return;
    const float* hp = h2 + (long)n * NCLASS;
    float s = 0.f, d = 0.f;
    #pragma unroll
    for (int c = 0; c < NCLASS; c++) {
        float v = hp[c];
        s += v * As[c];
        d += v * Ad[c];
    }
    e2s[n] = s; e2d[n] = d;
}

// ---------------- layer-2 fused: ONLINE softmax-agg + bias + log_softmax -----
__global__ __launch_bounds__(256) void gat2_logsm(
    const int* __restrict__ row_ptr, const int* __restrict__ eadj,
    const float* __restrict__ e2s, const float* __restrict__ e2d,
    const float* __restrict__ h2, const float* __restrict__ b2,
    float* __restrict__ out0) {
    int wave = threadIdx.x >> 6, lane = threadIdx.x & 63;
    int d = blockIdx.x * 4 + wave;
    if (d >= NN) return;
    int eslot = lane >> 3, c8 = lane & 7;
    float edv = e2d[d];
    int beg = row_ptr[d], end = row_ptr[d + 1];

    float mself = lrelu(e2s[d] + edv);
    float m = mself;
    float den = (eslot == 0) ? 1.f : 0.f;
    float acc[5];
    {
        const float* hp = h2 + (long)d * NCLASS + c8 * 5;
        #pragma unroll
        for (int k = 0; k < 5; k++) acc[k] = (eslot == 0) ? hp[k] : 0.f;
    }

    int sPre = (beg + eslot < end) ? eadj[beg + eslot] : 0;
    for (int i = beg; i < end; i += 8) {
        int idx = i + eslot;
        int s = sPre;
        if (i + 8 < end) {                        // prefetch next group's index
            int nidx = idx + 8;
            sPre = (nidx < end) ? eadj[nidx] : 0;
        }
        float el = lrelu(e2s[s] + edv);
        if (idx >= end) el = -1e30f;
        float gm = el;
        gm = fmaxf(gm, __shfl_xor(gm, 8));
        gm = fmaxf(gm, __shfl_xor(gm, 16));
        gm = fmaxf(gm, __shfl_xor(gm, 32));
        float mn = fmaxf(m, gm);
        float rsc = __expf(m - mn);        // 1.0 when no growth
        m = mn;
        den *= rsc;
        #pragma unroll
        for (int k = 0; k < 5; k++) acc[k] *= rsc;
        float wj = (idx < end) ? __expf(el - m) : 0.f;
        den += wj;
        if (idx < end) {
            const float* hp = h2 + (long)s * NCLASS + c8 * 5;
            #pragma unroll
            for (int k = 0; k < 5; k++) acc[k] += wj * hp[k];
        }
    }
    #pragma unroll
    for (int off = 8; off <= 32; off <<= 1) {
        den += __shfl_xor(den, off);
        #pragma unroll
        for (int k = 0; k < 5; k++) acc[k] += __shfl_xor(acc[k], off);
    }
    float inv = 1.f / den;
    float v[5];
    float mx = -1e30f;
    #pragma unroll
    for (int k = 0; k < 5; k++) {
        v[k] = acc[k] * inv + b2[c8 * 5 + k];
        mx = fmaxf(mx, v[k]);
    }
    #pragma unroll
    for (int off = 1; off <= 4; off <<= 1) mx = fmaxf(mx, __shfl_xor(mx, off));
    float sm = 0.f;
    #pragma unroll
    for (int k = 0; k < 5; k++) sm += __expf(v[k] - mx);
    #pragma unroll
    for (int off = 1; off <= 4; off <<= 1) sm += __shfl_xor(sm, off);
    float ls = mx + logf(sm);
    if (eslot == 0) {
        float* op = out0 + (long)d * NCLASS + c8 * 5;
        #pragma unroll
        for (int k = 0; k < 5; k++) op[k] = v[k] - ls;
    }
}

extern "C" void kernel_launch(void* const* d_in, const int* in_sizes, int n_in,
                              void* d_out, int out_size, void* d_ws, size_t ws_size,
                              hipStream_t stream) {
    const float* x   = (const float*)d_in[0];
    const int* ei    = (const int*)d_in[1];
    const float* W1  = (const float*)d_in[2];
    const float* as1 = (const float*)d_in[3];
    const float* ad1 = (const float*)d_in[4];
    const float* b1  = (const float*)d_in[5];
    const float* W2  = (const float*)d_in[6];
    const float* as2 = (const float*)d_in[7];
    const float* ad2 = (const float*)d_in[8];
    const float* b2  = (const float*)d_in[9];

    float* out0 = (float*)d_out;                   // [N,40] log_softmax
    float* h1o  = out0 + (long)NN * NCLASS;        // [N,256] h1 (fp32)

    // workspace layout
    unsigned short* hb = (unsigned short*)d_ws;               // N*F1 bf16 (51.2 MB)
    unsigned short* w1p = hb + (long)NN * F1;                 // 256*512 bf16 (packed)
    float* es1  = (float*)(w1p + F1 * NFEAT);                 // N*8
    float* ed1  = es1 + NN * HEADS;
    float* e2s  = ed1 + NN * HEADS;                           // N
    float* e2d  = e2s + NN;
    int* srcC   = (int*)(e2d + NN);                           // E
    int* dstC   = srcC + EE;                                  // E
    int* eadj   = dstC + EE;                                  // E
    int* deg    = eadj + EE;                                  // N
    int* row_ptr= deg + NN;                                   // N+1
    int* pos    = row_ptr + NN + 1;                           // N
    int* bsum   = pos + NN;                                   // NB1
    int* flag   = bsum + NB1;                                 // 1
    float* h2   = (float*)d_ws;                               // alias: N*40 (hb dead after gat1)

    hipMemsetAsync(flag, 0, 4, stream);
    hipMemsetAsync(deg, 0, (size_t)NN * 4, stream);

    // edge canonicalization + CSR build (canon fused with degree count)
    detect_i64<<<16, 256, 0, stream>>>(ei, flag);
    canon_edges<<<(EE + 255) / 256, 256, 0, stream>>>(ei, flag, srcC, dstC, deg);
    scan1<<<NB1, 256, 0, stream>>>(deg, bsum);
    scan2<<<1, 64, 0, stream>>>(bsum, row_ptr);
    scan3<<<NB1, 256, 0, stream>>>(deg, bsum, row_ptr, pos);
    fill_csr<<<(EE + 255) / 256, 256, 0, stream>>>(srcC, dstC, pos, eadj);

    // layer 1 (escore1 fused into gemm1 epilogue)
    prep_w1<<<(NFEAT * F1 + 255) / 256, 256, 0, stream>>>(W1, w1p);
    gemm1_kernel<<<(NN + 63) / 64, 256, 0, stream>>>(x, w1p, as1, ad1, hb, es1, ed1);
    gat1_fused<<<(NN + 3) / 4, 256, 0, stream>>>(row_ptr, eadj, es1, ed1, hb, b1, h1o);

    // layer 2
    gemm2_kernel<<<(int)(((long)NN * 10 + 255) / 256), 256, 0, stream>>>(h1o, W2, h2);
    escore2_kernel<<<(NN + 255) / 256, 256, 0, stream>>>(h2, as2, ad2, e2s, e2d);
    gat2_logsm<<<(NN + 3) / 4, 256, 0, stream>>>(row_ptr, eadj, e2s, e2d, h2, b2, out0);
}

// Round 7
// 702.184 us; speedup vs baseline: 1.0551x; 1.0110x over previous
//
#include <hip/hip_runtime.h>

#define NN 100000
#define EE 1000000
#define NFEAT 512
#define NHID 32
#define HEADS 8
#define F1 256               // HEADS*NHID
#define NCLASS 40
#define SLOPE 0.2f
#define NB1 98               // ceil(NN/1024) scan blocks

typedef __bf16 bf16x8 __attribute__((ext_vector_type(8)));
typedef float f32x4 __attribute__((ext_vector_type(4)));

union BF8 { unsigned short s[8]; bf16x8 v; uint4 u; };

__device__ __forceinline__ float bf2f(unsigned short u) {
    return __uint_as_float(((unsigned)u) << 16);
}
__device__ __forceinline__ unsigned short f2bf(float f) {
    unsigned x = __float_as_uint(f);
    unsigned r = (x + 0x7fffu + ((x >> 16) & 1u)) >> 16;
    return (unsigned short)r;
}
__device__ __forceinline__ float lrelu(float x) { return x > 0.f ? x : SLOPE * x; }

// ---------------- edge-index canonicalization (int32 vs int64 layout) --------
__global__ void detect_i64(const int* __restrict__ ei, int* __restrict__ flag) {
    int i = blockIdx.x * 256 + threadIdx.x;
    if (i < 4096) {
        if (ei[2 * i + 1] != 0) atomicOr(flag, 1);   // int64 LE high words are 0
    }
}
// canon + degree count fused (saves one 4MB edge-list pass)
__global__ void canon_edges(const int* __restrict__ ei, const int* __restrict__ flag,
                            int* __restrict__ srcC, int* __restrict__ dstC,
                            int* __restrict__ deg) {
    int e = blockIdx.x * 256 + threadIdx.x;
    if (e >= EE) return;
    int s, d;
    if (*flag) {               // int32 layout
        s = ei[e];
        d = ei[EE + e];
    } else {                   // int64 little-endian layout: read full 8B words
        int2 a = ((const int2*)ei)[e];
        int2 b = ((const int2*)ei)[EE + e];
        s = a.x;
        d = b.x;
    }
    srcC[e] = s;
    dstC[e] = d;
    atomicAdd(deg + d, 1);
}

// ---------------- CSR build: scan, fill ----------------
__global__ void scan1(const int* __restrict__ deg, int* __restrict__ bsum) {
    __shared__ int s[256];
    int b = blockIdx.x, t = threadIdx.x;
    int base = b * 1024 + t * 4, sum = 0;
    #pragma unroll
    for (int j = 0; j < 4; j++) { int i = base + j; sum += (i < NN) ? deg[i] : 0; }
    s[t] = sum; __syncthreads();
    for (int off = 128; off > 0; off >>= 1) {
        if (t < off) s[t] += s[t + off];
        __syncthreads();
    }
    if (t == 0) bsum[b] = s[0];
}
// wave-parallel exclusive scan of NB1=98 block sums
__global__ void scan2(int* __restrict__ bsum, int* __restrict__ row_ptr) {
    int lane = threadIdx.x;                      // single wave of 64
    int v0 = (lane < NB1) ? bsum[lane] : 0;
    int v1 = (64 + lane < NB1) ? bsum[64 + lane] : 0;
    int s0 = v0;
    #pragma unroll
    for (int off = 1; off < 64; off <<= 1) {
        int t = __shfl_up(s0, off);
        if (lane >= off) s0 += t;
    }
    int tot0 = __shfl(s0, 63);
    int s1 = v1;
    #pragma unroll
    for (int off = 1; off < 64; off <<= 1) {
        int t = __shfl_up(s1, off);
        if (lane >= off) s1 += t;
    }
    s1 += tot0;
    if (lane < NB1) bsum[lane] = s0 - v0;        // exclusive
    if (64 + lane < NB1) bsum[64 + lane] = s1 - v1;
    if (lane == 0) row_ptr[NN] = EE;
}
__global__ void scan3(const int* __restrict__ deg, const int* __restrict__ bsum,
                      int* __restrict__ row_ptr, int* __restrict__ pos) {
    __shared__ int ts[256];
    int b = blockIdx.x, t = threadIdx.x;
    int base = b * 1024 + t * 4;
    int v[4], sum = 0;
    #pragma unroll
    for (int j = 0; j < 4; j++) { int i = base + j; v[j] = (i < NN) ? deg[i] : 0; sum += v[j]; }
    ts[t] = sum; __syncthreads();
    for (int off = 1; off < 256; off <<= 1) {
        int add = (t >= off) ? ts[t - off] : 0;
        __syncthreads();
        ts[t] += add;
        __syncthreads();
    }
    int prefix = bsum[b] + ts[t] - sum;          // exclusive prefix for this thread
    #pragma unroll
    for (int j = 0; j < 4; j++) {
        int i = base + j;
        if (i < NN) { row_ptr[i] = prefix; pos[i] = prefix; prefix += v[j]; }
    }
}
__global__ void fill_csr(const int* __restrict__ srcC, const int* __restrict__ dstC,
                         int* __restrict__ pos, int* __restrict__ eadj) {
    int e = blockIdx.x * 256 + threadIdx.x;
    if (e >= EE) return;
    int idx = atomicAdd(pos + dstC[e], 1);
    eadj[idx] = srcC[e];
}

// ---------------- W1 prep: fp32 [512,256] -> PACKED bf16 staging order -------
// w1p element o = ((kk*16 + t)*4 + quad)*128 + r*8 + u  holds
// W1[kk*32 + quad*8 + u][t*16 + r]  (bf16).  Staging source is LINEAR:
// lds chunk p of k-step kk reads w1p + (kk*1024+p)*8 (coalesced), LDS dest
// linear, ds_read linear-in-lane (0 bank conflicts).
__global__ void prep_w1(const float* __restrict__ w1, unsigned short* __restrict__ w1p) {
    int o = blockIdx.x * 256 + threadIdx.x;
    if (o < NFEAT * F1) {
        int u = o & 7;
        int r = (o >> 3) & 15;
        int quad = (o >> 7) & 3;
        int t = (o >> 9) & 15;
        int kk = o >> 13;
        int k = kk * 32 + quad * 8 + u;
        int n = t * 16 + r;
        w1p[o] = f2bf(w1[k * F1 + n]);
    }
}

// ---------------- GEMM1 + fused escore1 ----------------
// M-tile = 128 rows, 8 waves x 16 rows, 512-thread blocks (R6 change).
// Rationale: R5 counters showed gemm1 latency-bound (Occ 18%, all utils low).
// 8 waves/block halves LDS-per-wave (occupancy ceiling 2x), halves block count
// (782) and W1 re-staging traffic, and gives the barrier drains 2x the resident
// waves to overlap with (m114 mechanism).  Inner loop unchanged.
__device__ __forceinline__ void stage_b(const unsigned short* __restrict__ w1p,
                                        unsigned short* bs, int kk, int tid) {
    #pragma unroll
    for (int j = 0; j < 2; j++) {
        int p = j * 512 + tid;                   // chunk position 0..1023
        const unsigned short* src = w1p + (kk * 1024 + p) * 8;
        unsigned short* dst = bs + p * 8;
        __builtin_amdgcn_global_load_lds(
            (const __attribute__((address_space(1))) unsigned int*)src,
            (__attribute__((address_space(3))) unsigned int*)dst, 16, 0, 0);
    }
}

__global__ __launch_bounds__(512) void gemm1_kernel(
    const float* __restrict__ x, const unsigned short* __restrict__ w1p,
    const float* __restrict__ a_src, const float* __restrict__ a_dst,
    unsigned short* __restrict__ hb, float* __restrict__ es, float* __restrict__ ed) {
    __shared__ unsigned short Bs[2][256 * 32];   // 2 x 16 KB
    __shared__ float As_[F1], Ad_[F1];
    int tid = threadIdx.x;
    if (tid < F1) {                              // first barrier covers this
        As_[tid] = a_src[tid];
        Ad_[tid] = a_dst[tid];
    }
    int wave = tid >> 6, lane = tid & 63;
    int quad = lane >> 4, r = lane & 15;
    int mBase = blockIdx.x * 128 + wave * 16;
    long arow = mBase + r; if (arow > NN - 1) arow = NN - 1;
    const float* aptr = x + arow * NFEAT + quad * 8;

    // prologue: stage Bs[0] and issue A-loads for kk=0
    stage_b(w1p, Bs[0], 0, tid);
    float4 fa0 = *(const float4*)(aptr);
    float4 fa1 = *(const float4*)(aptr + 4);

    f32x4 acc[16];
    #pragma unroll
    for (int t = 0; t < 16; t++) acc[t] = {0.f, 0.f, 0.f, 0.f};

    for (int kk = 0; kk < 16; kk++) {
        __syncthreads();                          // drains stage(kk) + fa(kk)
        float4 nf0, nf1;
        if (kk + 1 < 16) {                        // issue next-step loads early:
            stage_b(w1p, Bs[(kk + 1) & 1], kk + 1, tid);    // B -> other buffer
            nf0 = *(const float4*)(aptr + (kk + 1) * 32);   // A -> regs
            nf1 = *(const float4*)(aptr + (kk + 1) * 32 + 4);
        }
        float fa[8] = {fa0.x, fa0.y, fa0.z, fa0.w, fa1.x, fa1.y, fa1.z, fa1.w};
        BF8 ah;
        #pragma unroll
        for (int j = 0; j < 8; j++) ah.s[j] = f2bf(fa[j]);
        const unsigned short* bsc = Bs[kk & 1];
        #pragma unroll
        for (int t = 0; t < 16; t++) {
            BF8 vb;
            // linear layout: chunk p = t*64 + lane -> shorts offset p*8
            vb.u = *(const uint4*)(bsc + (t * 64 + quad * 16 + r) * 8);
            acc[t] = __builtin_amdgcn_mfma_f32_16x16x32_bf16(ah.v, vb.v, acc[t], 0, 0, 0);
        }
        if (kk + 1 < 16) { fa0 = nf0; fa1 = nf1; }
    }
    // epilogue: store bf16 row + per-head a_src/a_dst partial dots
    #pragma unroll
    for (int i = 0; i < 4; i++) {
        int m = mBase + quad * 4 + i;
        if (m < NN) {
            unsigned short* hp = hb + (long)m * F1 + r;
            #pragma unroll
            for (int t = 0; t < 16; t++) hp[t * 16] = f2bf(acc[t][i]);
        }
        float pv[16];
        #pragma unroll
        for (int k = 0; k < 16; k++) pv[k] = 0.f;
        #pragma unroll
        for (int t = 0; t < 16; t++) {
            float hv = bf2f(f2bf(acc[t][i]));    // same rounded value escore read
            int hd = t >> 1;
            pv[hd]     += hv * As_[t * 16 + r];
            pv[8 + hd] += hv * Ad_[t * 16 + r];
        }
        #pragma unroll
        for (int b = 1; b <= 8; b <<= 1) {
            #pragma unroll
            for (int k = 0; k < 16; k++) pv[k] += __shfl_xor(pv[k], b);
        }
        if (m < NN) {
            float v = pv[0];
            #pragma unroll
            for (int k = 1; k < 16; k++) v = (r == k) ? pv[k] : v;
            int hd = r & 7;
            if (r < 8) es[(long)m * 8 + hd] = v;
            else       ed[(long)m * 8 + hd] = v;
        }
    }
}

// ---------------- layer-1 fused: ONLINE softmax + aggregate + bias + ELU -----
// one wave per dst; 8 edges x 8 heads score lanes; 2-half x 16B gather lanes;
// eadj for the NEXT group prefetched one iteration ahead.
__global__ __launch_bounds__(256) void gat1_fused(
    const int* __restrict__ row_ptr, const int* __restrict__ eadj,
    const float* __restrict__ es, const float* __restrict__ ed,
    const unsigned short* __restrict__ hb, const float* __restrict__ b1,
    float* __restrict__ h1o) {
    int wave = threadIdx.x >> 6, lane = threadIdx.x & 63;
    int d = blockIdx.x * 4 + wave;
    if (d >= NN) return;
    int eslot = lane >> 3, hd8 = lane & 7;
    int half = lane >> 5, sub = lane & 31, hh = sub >> 2;
    float edv = ed[d * 8 + hd8];
    int beg = row_ptr[d], end = row_ptr[d + 1];

    float mself = lrelu(es[d * 8 + hd8] + edv);
    float m = mself;
    float den = (eslot == 0) ? 1.f : 0.f;

    float a0, a1, a2, a3, a4, a5, a6, a7;
    if (half == 0) {                              // self row, weight 1
        uint4 u = ((const uint4*)(hb + (long)d * F1))[sub];
        a0 = bf2f((unsigned short)(u.x & 0xffffu)); a1 = bf2f((unsigned short)(u.x >> 16));
        a2 = bf2f((unsigned short)(u.y & 0xffffu)); a3 = bf2f((unsigned short)(u.y >> 16));
        a4 = bf2f((unsigned short)(u.z & 0xffffu)); a5 = bf2f((unsigned short)(u.z >> 16));
        a6 = bf2f((unsigned short)(u.w & 0xffffu)); a7 = bf2f((unsigned short)(u.w >> 16));
    } else {
        a0 = a1 = a2 = a3 = a4 = a5 = a6 = a7 = 0.f;
    }

    int sPre = (beg + eslot < end) ? eadj[beg + eslot] : 0;
    for (int i = beg; i < end; i += 8) {
        int idx = i + eslot;
        int s = sPre;
        if (i + 8 < end) {                        // prefetch next group's index
            int nidx = idx + 8;
            sPre = (nidx < end) ? eadj[nidx] : 0;
        }
        float el = lrelu(es[s * 8 + hd8] + edv);
        if (idx >= end) el = -1e30f;
        float gm = el;
        gm = fmaxf(gm, __shfl_xor(gm, 8));
        gm = fmaxf(gm, __shfl_xor(gm, 16));
        gm = fmaxf(gm, __shfl_xor(gm, 32));
        float mn = fmaxf(m, gm);
        float rsc = __expf(m - mn);               // == 1.0 exactly when no growth
        m = mn;
        den *= rsc;
        float wj = (idx < end) ? __expf(el - m) : 0.f;
        den += wj;
        float ro = __shfl(rsc, hh);               // rescale factor for col-head hh
        a0 *= ro; a1 *= ro; a2 *= ro; a3 *= ro;
        a4 *= ro; a5 *= ro; a6 *= ro; a7 *= ro;

        int cnt = min(8, end - i);
        #pragma unroll
        for (int jj = 0; jj < 4; jj++) {
            int e = jj * 2 + half;
            float w = __shfl(wj, e * 8 + hh);
            int sj = __shfl(s, e * 8);
            if (e < cnt) {
                uint4 u = ((const uint4*)(hb + (long)sj * F1))[sub];
                a0 += w * bf2f((unsigned short)(u.x & 0xffffu));
                a1 += w * bf2f((unsigned short)(u.x >> 16));
                a2 += w * bf2f((unsigned short)(u.y & 0xffffu));
                a3 += w * bf2f((unsigned short)(u.y >> 16));
                a4 += w * bf2f((unsigned short)(u.z & 0xffffu));
                a5 += w * bf2f((unsigned short)(u.z >> 16));
                a6 += w * bf2f((unsigned short)(u.w & 0xffffu));
                a7 += w * bf2f((unsigned short)(u.w >> 16));
            }
        }
    }
    den += __shfl_xor(den, 8);
    den += __shfl_xor(den, 16);
    den += __shfl_xor(den, 32);
    float deno = __shfl(den, hh);

    a0 += __shfl_xor(a0, 32); a1 += __shfl_xor(a1, 32);
    a2 += __shfl_xor(a2, 32); a3 += __shfl_xor(a3, 32);
    a4 += __shfl_xor(a4, 32); a5 += __shfl_xor(a5, 32);
    a6 += __shfl_xor(a6, 32); a7 += __shfl_xor(a7, 32);

    if (half == 0) {
        float inv = 1.f / deno;
        float4 blo = ((const float4*)b1)[sub * 2];
        float4 bhi = ((const float4*)b1)[sub * 2 + 1];
        float r0 = a0 * inv + blo.x, r1 = a1 * inv + blo.y;
        float r2 = a2 * inv + blo.z, r3 = a3 * inv + blo.w;
        float r4 = a4 * inv + bhi.x, r5 = a5 * inv + bhi.y;
        float r6 = a6 * inv + bhi.z, r7 = a7 * inv + bhi.w;
        r0 = r0 > 0.f ? r0 : expm1f(r0); r1 = r1 > 0.f ? r1 : expm1f(r1);
        r2 = r2 > 0.f ? r2 : expm1f(r2); r3 = r3 > 0.f ? r3 : expm1f(r3);
        r4 = r4 > 0.f ? r4 : expm1f(r4); r5 = r5 > 0.f ? r5 : expm1f(r5);
        r6 = r6 > 0.f ? r6 : expm1f(r6); r7 = r7 > 0.f ? r7 : expm1f(r7);
        float4 o0 = {r0, r1, r2, r3}, o1 = {r4, r5, r6, r7};
        ((float4*)(h1o + (long)d * F1))[sub * 2] = o0;
        ((float4*)(h1o + (long)d * F1))[sub * 2 + 1] = o1;
    }
}

// ---------------- GEMM2: h2[N,40] = h1[N,256] @ W2 (fp32, W2 in LDS) ----------
__global__ __launch_bounds__(256) void gemm2_kernel(const float* __restrict__ h1,
                                                    const float* __restrict__ w2,
                                                    float* __restrict__ h2) {
    __shared__ float4 Ws[F1 * 10];
    for (int i = threadIdx.x; i < F1 * 10; i += 256) Ws[i] = ((const float4*)w2)[i];
    __syncthreads();
    long t = (long)blockIdx.x * 256 + threadIdx.x;
    if (t >= (long)NN * 10) return;
    int n = (int)(t / 10);
    int j = (int)(t - (long)n * 10);
    const float4* hp = (const float4*)(h1 + (long)n * F1);
    float4 a = {0.f, 0.f, 0.f, 0.f};
    #pragma unroll 8
    for (int k4 = 0; k4 < 64; k4++) {
        float4 hv = hp[k4];
        float4 w0 = Ws[(k4 * 4 + 0) * 10 + j];
        float4 w1v = Ws[(k4 * 4 + 1) * 10 + j];
        float4 w2v = Ws[(k4 * 4 + 2) * 10 + j];
        float4 w3v = Ws[(k4 * 4 + 3) * 10 + j];
        a.x += hv.x * w0.x + hv.y * w1v.x + hv.z * w2v.x + hv.w * w3v.x;
        a.y += hv.x * w0.y + hv.y * w1v.y + hv.z * w2v.y + hv.w * w3v.y;
        a.z += hv.x * w0.z + hv.y * w1v.z + hv.z * w2v.z + hv.w * w3v.z;
        a.w += hv.x * w0.w + hv.y * w1v.w + hv.z * w2v.w + hv.w * w3v.w;
    }
    ((float4*)(h2 + (long)n * NCLASS))[j] = a;
}

// ---------------- e_src/e_dst layer2 ----------------
__global__ void escore2_kernel(const float* __restrict__ h2,
                               const float* __restrict__ a_src2,
                               const float* __restrict__ a_dst2,
                               float* __restrict__ e2s, float* __restrict__ e2d) {
    __shared__ float As[NCLASS], Ad[NCLASS];
    if (threadIdx.x < NCLASS) {
        As[threadIdx.x] = a_src2[threadIdx.x];
        Ad[threadIdx.x] = a_dst2[threadIdx.x];
    }
    __syncthreads();
    int n = blockIdx.x * 256 + threadIdx.x;
    if (n >= NN) return;
    const float* hp = h2 + (long)n * NCLASS;
    float s = 0.f, d = 0.f;
    #pragma unroll
    for (int c = 0; c < NCLASS; c++) {
        float v = hp[c];
        s += v * As[c];
        d += v * Ad[c];
    }
    e2s[n] = s; e2d[n] = d;
}

// ---------------- layer-2 fused: ONLINE softmax-agg + bias + log_softmax -----
__global__ __launch_bounds__(256) void gat2_logsm(
    const int* __restrict__ row_ptr, const int* __restrict__ eadj,
    const float* __restrict__ e2s, const float* __restrict__ e2d,
    const float* __restrict__ h2, const float* __restrict__ b2,
    float* __restrict__ out0) {
    int wave = threadIdx.x >> 6, lane = threadIdx.x & 63;
    int d = blockIdx.x * 4 + wave;
    if (d >= NN) return;
    int eslot = lane >> 3, c8 = lane & 7;
    float edv = e2d[d];
    int beg = row_ptr[d], end = row_ptr[d + 1];

    float mself = lrelu(e2s[d] + edv);
    float m = mself;
    float den = (eslot == 0) ? 1.f : 0.f;
    float acc[5];
    {
        const float* hp = h2 + (long)d * NCLASS + c8 * 5;
        #pragma unroll
        for (int k = 0; k < 5; k++) acc[k] = (eslot == 0) ? hp[k] : 0.f;
    }

    int sPre = (beg + eslot < end) ? eadj[beg + eslot] : 0;
    for (int i = beg; i < end; i += 8) {
        int idx = i + eslot;
        int s = sPre;
        if (i + 8 < end) {                        // prefetch next group's index
            int nidx = idx + 8;
            sPre = (nidx < end) ? eadj[nidx] : 0;
        }
        float el = lrelu(e2s[s] + edv);
        if (idx >= end) el = -1e30f;
        float gm = el;
        gm = fmaxf(gm, __shfl_xor(gm, 8));
        gm = fmaxf(gm, __shfl_xor(gm, 16));
        gm = fmaxf(gm, __shfl_xor(gm, 32));
        float mn = fmaxf(m, gm);
        float rsc = __expf(m - mn);        // 1.0 when no growth
        m = mn;
        den *= rsc;
        #pragma unroll
        for (int k = 0; k < 5; k++) acc[k] *= rsc;
        float wj = (idx < end) ? __expf(el - m) : 0.f;
        den += wj;
        if (idx < end) {
            const float* hp = h2 + (long)s * NCLASS + c8 * 5;
            #pragma unroll
            for (int k = 0; k < 5; k++) acc[k] += wj * hp[k];
        }
    }
    #pragma unroll
    for (int off = 8; off <= 32; off <<= 1) {
        den += __shfl_xor(den, off);
        #pragma unroll
        for (int k = 0; k < 5; k++) acc[k] += __shfl_xor(acc[k], off);
    }
    float inv = 1.f / den;
    float v[5];
    float mx = -1e30f;
    #pragma unroll
    for (int k = 0; k < 5; k++) {
        v[k] = acc[k] * inv + b2[c8 * 5 + k];
        mx = fmaxf(mx, v[k]);
    }
    #pragma unroll
    for (int off = 1; off <= 4; off <<= 1) mx = fmaxf(mx, __shfl_xor(mx, off));
    float sm = 0.f;
    #pragma unroll
    for (int k = 0; k < 5; k++) sm += __expf(v[k] - mx);
    #pragma unroll
    for (int off = 1; off <= 4; off <<= 1) sm += __shfl_xor(sm, off);
    float ls = mx + logf(sm);
    if (eslot == 0) {
        float* op = out0 + (long)d * NCLASS + c8 * 5;
        #pragma unroll
        for (int k = 0; k < 5; k++) op[k] = v[k] - ls;
    }
}

extern "C" void kernel_launch(void* const* d_in, const int* in_sizes, int n_in,
                              void* d_out, int out_size, void* d_ws, size_t ws_size,
                              hipStream_t stream) {
    const float* x   = (const float*)d_in[0];
    const int* ei    = (const int*)d_in[1];
    const float* W1  = (const float*)d_in[2];
    const float* as1 = (const float*)d_in[3];
    const float* ad1 = (const float*)d_in[4];
    const float* b1  = (const float*)d_in[5];
    const float* W2  = (const float*)d_in[6];
    const float* as2 = (const float*)d_in[7];
    const float* ad2 = (const float*)d_in[8];
    const float* b2  = (const float*)d_in[9];

    float* out0 = (float*)d_out;                   // [N,40] log_softmax
    float* h1o  = out0 + (long)NN * NCLASS;        // [N,256] h1 (fp32)

    // workspace layout
    unsigned short* hb = (unsigned short*)d_ws;               // N*F1 bf16 (51.2 MB)
    unsigned short* w1p = hb + (long)NN * F1;                 // 256*512 bf16 (packed)
    float* es1  = (float*)(w1p + F1 * NFEAT);                 // N*8
    float* ed1  = es1 + NN * HEADS;
    float* e2s  = ed1 + NN * HEADS;                           // N
    float* e2d  = e2s + NN;
    int* srcC   = (int*)(e2d + NN);                           // E
    int* dstC   = srcC + EE;                                  // E
    int* eadj   = dstC + EE;                                  // E
    int* deg    = eadj + EE;                                  // N
    int* row_ptr= deg + NN;                                   // N+1
    int* pos    = row_ptr + NN + 1;                           // N
    int* bsum   = pos + NN;                                   // NB1
    int* flag   = bsum + NB1;                                 // 1
    float* h2   = (float*)d_ws;                               // alias: N*40 (hb dead after gat1)

    hipMemsetAsync(flag, 0, 4, stream);
    hipMemsetAsync(deg, 0, (size_t)NN * 4, stream);

    // edge canonicalization + CSR build (canon fused with degree count)
    detect_i64<<<16, 256, 0, stream>>>(ei, flag);
    canon_edges<<<(EE + 255) / 256, 256, 0, stream>>>(ei, flag, srcC, dstC, deg);
    scan1<<<NB1, 256, 0, stream>>>(deg, bsum);
    scan2<<<1, 64, 0, stream>>>(bsum, row_ptr);
    scan3<<<NB1, 256, 0, stream>>>(deg, bsum, row_ptr, pos);
    fill_csr<<<(EE + 255) / 256, 256, 0, stream>>>(srcC, dstC, pos, eadj);

    // layer 1 (escore1 fused into gemm1 epilogue; 128-row M-tile, 8 waves)
    prep_w1<<<(NFEAT * F1 + 255) / 256, 256, 0, stream>>>(W1, w1p);
    gemm1_kernel<<<(NN + 127) / 128, 512, 0, stream>>>(x, w1p, as1, ad1, hb, es1, ed1);
    gat1_fused<<<(NN + 3) / 4, 256, 0, stream>>>(row_ptr, eadj, es1, ed1, hb, b1, h1o);

    // layer 2
    gemm2_kernel<<<(int)(((long)NN * 10 + 255) / 256), 256, 0, stream>>>(h1o, W2, h2);
    escore2_kernel<<<(NN + 255) / 256, 256, 0, stream>>>(h2, as2, ad2, e2s, e2d);
    gat2_logsm<<<(NN + 3) / 4, 256, 0, stream>>>(row_ptr, eadj, e2s, e2d, h2, b2, out0);
}

// Round 8
// 701.870 us; speedup vs baseline: 1.0556x; 1.0004x over previous
//
#include <hip/hip_runtime.h>

#define NN 100000
#define EE 1000000
#define NFEAT 512
#define NHID 32
#define HEADS 8
#define F1 256               // HEADS*NHID
#define NCLASS 40
#define SLOPE 0.2f
#define NB1 98               // ceil(NN/1024) scan blocks

typedef __bf16 bf16x8 __attribute__((ext_vector_type(8)));
typedef float f32x4 __attribute__((ext_vector_type(4)));

union BF8 { unsigned short s[8]; bf16x8 v; uint4 u; };

__device__ __forceinline__ float bf2f(unsigned short u) {
    return __uint_as_float(((unsigned)u) << 16);
}
__device__ __forceinline__ unsigned short f2bf(float f) {
    unsigned x = __float_as_uint(f);
    unsigned r = (x + 0x7fffu + ((x >> 16) & 1u)) >> 16;
    return (unsigned short)r;
}
__device__ __forceinline__ float lrelu(float x) { return x > 0.f ? x : SLOPE * x; }

// ---------------- edge-index canonicalization (int32 vs int64 layout) --------
__global__ void detect_i64(const int* __restrict__ ei, int* __restrict__ flag) {
    int i = blockIdx.x * 256 + threadIdx.x;
    if (i < 4096) {
        if (ei[2 * i + 1] != 0) atomicOr(flag, 1);   // int64 LE high words are 0
    }
}
// canon + degree count fused (saves one 4MB edge-list pass)
__global__ void canon_edges(const int* __restrict__ ei, const int* __restrict__ flag,
                            int* __restrict__ srcC, int* __restrict__ dstC,
                            int* __restrict__ deg) {
    int e = blockIdx.x * 256 + threadIdx.x;
    if (e >= EE) return;
    int s, d;
    if (*flag) {               // int32 layout
        s = ei[e];
        d = ei[EE + e];
    } else {                   // int64 little-endian layout: read full 8B words
        int2 a = ((const int2*)ei)[e];
        int2 b = ((const int2*)ei)[EE + e];
        s = a.x;
        d = b.x;
    }
    srcC[e] = s;
    dstC[e] = d;
    atomicAdd(deg + d, 1);
}

// ---------------- CSR build: scan, fill ----------------
__global__ void scan1(const int* __restrict__ deg, int* __restrict__ bsum) {
    __shared__ int s[256];
    int b = blockIdx.x, t = threadIdx.x;
    int base = b * 1024 + t * 4, sum = 0;
    #pragma unroll
    for (int j = 0; j < 4; j++) { int i = base + j; sum += (i < NN) ? deg[i] : 0; }
    s[t] = sum; __syncthreads();
    for (int off = 128; off > 0; off >>= 1) {
        if (t < off) s[t] += s[t + off];
        __syncthreads();
    }
    if (t == 0) bsum[b] = s[0];
}
// wave-parallel exclusive scan of NB1=98 block sums
__global__ void scan2(int* __restrict__ bsum, int* __restrict__ row_ptr) {
    int lane = threadIdx.x;                      // single wave of 64
    int v0 = (lane < NB1) ? bsum[lane] : 0;
    int v1 = (64 + lane < NB1) ? bsum[64 + lane] : 0;
    int s0 = v0;
    #pragma unroll
    for (int off = 1; off < 64; off <<= 1) {
        int t = __shfl_up(s0, off);
        if (lane >= off) s0 += t;
    }
    int tot0 = __shfl(s0, 63);
    int s1 = v1;
    #pragma unroll
    for (int off = 1; off < 64; off <<= 1) {
        int t = __shfl_up(s1, off);
        if (lane >= off) s1 += t;
    }
    s1 += tot0;
    if (lane < NB1) bsum[lane] = s0 - v0;        // exclusive
    if (64 + lane < NB1) bsum[64 + lane] = s1 - v1;
    if (lane == 0) row_ptr[NN] = EE;
}
__global__ void scan3(const int* __restrict__ deg, const int* __restrict__ bsum,
                      int* __restrict__ row_ptr, int* __restrict__ pos) {
    __shared__ int ts[256];
    int b = blockIdx.x, t = threadIdx.x;
    int base = b * 1024 + t * 4;
    int v[4], sum = 0;
    #pragma unroll
    for (int j = 0; j < 4; j++) { int i = base + j; v[j] = (i < NN) ? deg[i] : 0; sum += v[j]; }
    ts[t] = sum; __syncthreads();
    for (int off = 1; off < 256; off <<= 1) {
        int add = (t >= off) ? ts[t - off] : 0;
        __syncthreads();
        ts[t] += add;
        __syncthreads();
    }
    int prefix = bsum[b] + ts[t] - sum;          // exclusive prefix for this thread
    #pragma unroll
    for (int j = 0; j < 4; j++) {
        int i = base + j;
        if (i < NN) { row_ptr[i] = prefix; pos[i] = prefix; prefix += v[j]; }
    }
}
__global__ void fill_csr(const int* __restrict__ srcC, const int* __restrict__ dstC,
                         int* __restrict__ pos, int* __restrict__ eadj) {
    int e = blockIdx.x * 256 + threadIdx.x;
    if (e >= EE) return;
    int idx = atomicAdd(pos + dstC[e], 1);
    eadj[idx] = srcC[e];
}

// ---------------- W1 prep: fp32 [512,256] -> PACKED bf16 staging order -------
// w1p element o = ((kk*16 + t)*4 + quad)*128 + r*8 + u  holds
// W1[kk*32 + quad*8 + u][t*16 + r]  (bf16).  Staging source is LINEAR:
// lds chunk p of k-step kk reads w1p + (kk*1024+p)*8 (coalesced), LDS dest
// linear, ds_read linear-in-lane (0 bank conflicts).
__global__ void prep_w1(const float* __restrict__ w1, unsigned short* __restrict__ w1p) {
    int o = blockIdx.x * 256 + threadIdx.x;
    if (o < NFEAT * F1) {
        int u = o & 7;
        int r = (o >> 3) & 15;
        int quad = (o >> 7) & 3;
        int t = (o >> 9) & 15;
        int kk = o >> 13;
        int k = kk * 32 + quad * 8 + u;
        int n = t * 16 + r;
        w1p[o] = f2bf(w1[k * F1 + n]);
    }
}

// ---------------- GEMM1 + fused escore1 ----------------
// M-tile = 128 rows, 8 waves x 16 rows, 512-thread blocks.
__device__ __forceinline__ void stage_b(const unsigned short* __restrict__ w1p,
                                        unsigned short* bs, int kk, int tid) {
    #pragma unroll
    for (int j = 0; j < 2; j++) {
        int p = j * 512 + tid;                   // chunk position 0..1023
        const unsigned short* src = w1p + (kk * 1024 + p) * 8;
        unsigned short* dst = bs + p * 8;
        __builtin_amdgcn_global_load_lds(
            (const __attribute__((address_space(1))) unsigned int*)src,
            (__attribute__((address_space(3))) unsigned int*)dst, 16, 0, 0);
    }
}

__global__ __launch_bounds__(512) void gemm1_kernel(
    const float* __restrict__ x, const unsigned short* __restrict__ w1p,
    const float* __restrict__ a_src, const float* __restrict__ a_dst,
    unsigned short* __restrict__ hb, float* __restrict__ es, float* __restrict__ ed) {
    __shared__ unsigned short Bs[2][256 * 32];   // 2 x 16 KB
    __shared__ float As_[F1], Ad_[F1];
    int tid = threadIdx.x;
    if (tid < F1) {                              // first barrier covers this
        As_[tid] = a_src[tid];
        Ad_[tid] = a_dst[tid];
    }
    int wave = tid >> 6, lane = tid & 63;
    int quad = lane >> 4, r = lane & 15;
    int mBase = blockIdx.x * 128 + wave * 16;
    long arow = mBase + r; if (arow > NN - 1) arow = NN - 1;
    const float* aptr = x + arow * NFEAT + quad * 8;

    // prologue: stage Bs[0] and issue A-loads for kk=0
    stage_b(w1p, Bs[0], 0, tid);
    float4 fa0 = *(const float4*)(aptr);
    float4 fa1 = *(const float4*)(aptr + 4);

    f32x4 acc[16];
    #pragma unroll
    for (int t = 0; t < 16; t++) acc[t] = {0.f, 0.f, 0.f, 0.f};

    for (int kk = 0; kk < 16; kk++) {
        __syncthreads();                          // drains stage(kk) + fa(kk)
        float4 nf0, nf1;
        if (kk + 1 < 16) {                        // issue next-step loads early:
            stage_b(w1p, Bs[(kk + 1) & 1], kk + 1, tid);    // B -> other buffer
            nf0 = *(const float4*)(aptr + (kk + 1) * 32);   // A -> regs
            nf1 = *(const float4*)(aptr + (kk + 1) * 32 + 4);
        }
        float fa[8] = {fa0.x, fa0.y, fa0.z, fa0.w, fa1.x, fa1.y, fa1.z, fa1.w};
        BF8 ah;
        #pragma unroll
        for (int j = 0; j < 8; j++) ah.s[j] = f2bf(fa[j]);
        const unsigned short* bsc = Bs[kk & 1];
        #pragma unroll
        for (int t = 0; t < 16; t++) {
            BF8 vb;
            // linear layout: chunk p = t*64 + lane -> shorts offset p*8
            vb.u = *(const uint4*)(bsc + (t * 64 + quad * 16 + r) * 8);
            acc[t] = __builtin_amdgcn_mfma_f32_16x16x32_bf16(ah.v, vb.v, acc[t], 0, 0, 0);
        }
        if (kk + 1 < 16) { fa0 = nf0; fa1 = nf1; }
    }
    // epilogue: store bf16 row + per-head a_src/a_dst partial dots
    #pragma unroll
    for (int i = 0; i < 4; i++) {
        int m = mBase + quad * 4 + i;
        if (m < NN) {
            unsigned short* hp = hb + (long)m * F1 + r;
            #pragma unroll
            for (int t = 0; t < 16; t++) hp[t * 16] = f2bf(acc[t][i]);
        }
        float pv[16];
        #pragma unroll
        for (int k = 0; k < 16; k++) pv[k] = 0.f;
        #pragma unroll
        for (int t = 0; t < 16; t++) {
            float hv = bf2f(f2bf(acc[t][i]));    // same rounded value escore read
            int hd = t >> 1;
            pv[hd]     += hv * As_[t * 16 + r];
            pv[8 + hd] += hv * Ad_[t * 16 + r];
        }
        #pragma unroll
        for (int b = 1; b <= 8; b <<= 1) {
            #pragma unroll
            for (int k = 0; k < 16; k++) pv[k] += __shfl_xor(pv[k], b);
        }
        if (m < NN) {
            float v = pv[0];
            #pragma unroll
            for (int k = 1; k < 16; k++) v = (r == k) ? pv[k] : v;
            int hd = r & 7;
            if (r < 8) es[(long)m * 8 + hd] = v;
            else       ed[(long)m * 8 + hd] = v;
        }
    }
}

// ---------------- layer-1 fused: ONLINE softmax + aggregate + bias + ELU -----
// one wave per dst; 8 edges x 8 heads score lanes; 2-half x 16B gather lanes.
// R8: two-deep prefetch — both the NEXT group's eadj index AND its es-score
// gather are issued one group ahead, hiding the chained index->score random
// load latency under the current group's row gathers + FMAs.  The online-
// softmax rescale is skipped via a wave-uniform branch when the group max
// doesn't grow (exact: rsc would be 1.0 bit-exactly; m,gm uniform per head).
__global__ __launch_bounds__(256) void gat1_fused(
    const int* __restrict__ row_ptr, const int* __restrict__ eadj,
    const float* __restrict__ es, const float* __restrict__ ed,
    const unsigned short* __restrict__ hb, const float* __restrict__ b1,
    float* __restrict__ h1o) {
    int wave = threadIdx.x >> 6, lane = threadIdx.x & 63;
    int d = blockIdx.x * 4 + wave;
    if (d >= NN) return;
    int eslot = lane >> 3, hd8 = lane & 7;
    int half = lane >> 5, sub = lane & 31, hh = sub >> 2;
    float edv = ed[d * 8 + hd8];
    int beg = row_ptr[d], end = row_ptr[d + 1];

    float mself = lrelu(es[d * 8 + hd8] + edv);
    float m = mself;
    float den = (eslot == 0) ? 1.f : 0.f;

    float a0, a1, a2, a3, a4, a5, a6, a7;
    if (half == 0) {                              // self row, weight 1
        uint4 u = ((const uint4*)(hb + (long)d * F1))[sub];
        a0 = bf2f((unsigned short)(u.x & 0xffffu)); a1 = bf2f((unsigned short)(u.x >> 16));
        a2 = bf2f((unsigned short)(u.y & 0xffffu)); a3 = bf2f((unsigned short)(u.y >> 16));
        a4 = bf2f((unsigned short)(u.z & 0xffffu)); a5 = bf2f((unsigned short)(u.z >> 16));
        a6 = bf2f((unsigned short)(u.w & 0xffffu)); a7 = bf2f((unsigned short)(u.w >> 16));
    } else {
        a0 = a1 = a2 = a3 = a4 = a5 = a6 = a7 = 0.f;
    }

    // group-0 prefetch: index AND score
    int sPre = (beg + eslot < end) ? eadj[beg + eslot] : 0;
    float elPre = lrelu(es[sPre * 8 + hd8] + edv);
    if (beg + eslot >= end) elPre = -1e30f;

    for (int i = beg; i < end; i += 8) {
        int idx = i + eslot;
        int s = sPre;
        float el = elPre;
        if (i + 8 < end) {                        // prefetch next group's chain
            int nidx = idx + 8;
            sPre = (nidx < end) ? eadj[nidx] : 0;
            float e1 = lrelu(es[sPre * 8 + hd8] + edv);
            elPre = (nidx < end) ? e1 : -1e30f;
        }
        float gm = el;
        gm = fmaxf(gm, __shfl_xor(gm, 8));
        gm = fmaxf(gm, __shfl_xor(gm, 16));
        gm = fmaxf(gm, __shfl_xor(gm, 32));
        if (__any(gm > m)) {                      // rescale only on max growth
            float mn = fmaxf(m, gm);
            float rsc = __expf(m - mn);
            m = mn;
            den *= rsc;
            float ro = __shfl(rsc, hh);           // factor for col-head hh
            a0 *= ro; a1 *= ro; a2 *= ro; a3 *= ro;
            a4 *= ro; a5 *= ro; a6 *= ro; a7 *= ro;
        }
        float wj = (idx < end) ? __expf(el - m) : 0.f;
        den += wj;

        int cnt = min(8, end - i);
        #pragma unroll
        for (int jj = 0; jj < 4; jj++) {
            int e = jj * 2 + half;
            float w = __shfl(wj, e * 8 + hh);
            int sj = __shfl(s, e * 8);
            if (e < cnt) {
                uint4 u = ((const uint4*)(hb + (long)sj * F1))[sub];
                a0 += w * bf2f((unsigned short)(u.x & 0xffffu));
                a1 += w * bf2f((unsigned short)(u.x >> 16));
                a2 += w * bf2f((unsigned short)(u.y & 0xffffu));
                a3 += w * bf2f((unsigned short)(u.y >> 16));
                a4 += w * bf2f((unsigned short)(u.z & 0xffffu));
                a5 += w * bf2f((unsigned short)(u.z >> 16));
                a6 += w * bf2f((unsigned short)(u.w & 0xffffu));
                a7 += w * bf2f((unsigned short)(u.w >> 16));
            }
        }
    }
    den += __shfl_xor(den, 8);
    den += __shfl_xor(den, 16);
    den += __shfl_xor(den, 32);
    float deno = __shfl(den, hh);

    a0 += __shfl_xor(a0, 32); a1 += __shfl_xor(a1, 32);
    a2 += __shfl_xor(a2, 32); a3 += __shfl_xor(a3, 32);
    a4 += __shfl_xor(a4, 32); a5 += __shfl_xor(a5, 32);
    a6 += __shfl_xor(a6, 32); a7 += __shfl_xor(a7, 32);

    if (half == 0) {
        float inv = 1.f / deno;
        float4 blo = ((const float4*)b1)[sub * 2];
        float4 bhi = ((const float4*)b1)[sub * 2 + 1];
        float r0 = a0 * inv + blo.x, r1 = a1 * inv + blo.y;
        float r2 = a2 * inv + blo.z, r3 = a3 * inv + blo.w;
        float r4 = a4 * inv + bhi.x, r5 = a5 * inv + bhi.y;
        float r6 = a6 * inv + bhi.z, r7 = a7 * inv + bhi.w;
        r0 = r0 > 0.f ? r0 : expm1f(r0); r1 = r1 > 0.f ? r1 : expm1f(r1);
        r2 = r2 > 0.f ? r2 : expm1f(r2); r3 = r3 > 0.f ? r3 : expm1f(r3);
        r4 = r4 > 0.f ? r4 : expm1f(r4); r5 = r5 > 0.f ? r5 : expm1f(r5);
        r6 = r6 > 0.f ? r6 : expm1f(r6); r7 = r7 > 0.f ? r7 : expm1f(r7);
        float4 o0 = {r0, r1, r2, r3}, o1 = {r4, r5, r6, r7};
        ((float4*)(h1o + (long)d * F1))[sub * 2] = o0;
        ((float4*)(h1o + (long)d * F1))[sub * 2 + 1] = o1;
    }
}

// ---------------- GEMM2: h2[N,40] = h1[N,256] @ W2 (fp32, W2 in LDS) ----------
__global__ __launch_bounds__(256) void gemm2_kernel(const float* __restrict__ h1,
                                                    const float* __restrict__ w2,
                                                    float* __restrict__ h2) {
    __shared__ float4 Ws[F1 * 10];
    for (int i = threadIdx.x; i < F1 * 10; i += 256) Ws[i] = ((const float4*)w2)[i];
    __syncthreads();
    long t = (long)blockIdx.x * 256 + threadIdx.x;
    if (t >= (long)NN * 10) return;
    int n = (int)(t / 10);
    int j = (int)(t - (long)n * 10);
    const float4* hp = (const float4*)(h1 + (long)n * F1);
    float4 a = {0.f, 0.f, 0.f, 0.f};
    #pragma unroll 8
    for (int k4 = 0; k4 < 64; k4++) {
        float4 hv = hp[k4];
        float4 w0 = Ws[(k4 * 4 + 0) * 10 + j];
        float4 w1v = Ws[(k4 * 4 + 1) * 10 + j];
        float4 w2v = Ws[(k4 * 4 + 2) * 10 + j];
        float4 w3v = Ws[(k4 * 4 + 3) * 10 + j];
        a.x += hv.x * w0.x + hv.y * w1v.x + hv.z * w2v.x + hv.w * w3v.x;
        a.y += hv.x * w0.y + hv.y * w1v.y + hv.z * w2v.y + hv.w * w3v.y;
        a.z += hv.x * w0.z + hv.y * w1v.z + hv.z * w2v.z + hv.w * w3v.z;
        a.w += hv.x * w0.w + hv.y * w1v.w + hv.z * w2v.w + hv.w * w3v.w;
    }
    ((float4*)(h2 + (long)n * NCLASS))[j] = a;
}

// ---------------- e_src/e_dst layer2 ----------------
__global__ void escore2_kernel(const float* __restrict__ h2,
                               const float* __restrict__ a_src2,
                               const float* __restrict__ a_dst2,
                               float* __restrict__ e2s, float* __restrict__ e2d) {
    __shared__ float As[NCLASS], Ad[NCLASS];
    if (threadIdx.x < NCLASS) {
        As[threadIdx.x] = a_src2[threadIdx.x];
        Ad[threadIdx.x] = a_dst2[threadIdx.x];
    }
    __syncthreads();
    int n = blockIdx.x * 256 + threadIdx.x;
    if (n >= NN) return;
    const float* hp = h2 + (long)n * NCLASS;
    float s = 0.f, d = 0.f;
    #pragma unroll
    for (int c = 0; c < NCLASS; c++) {
        float v = hp[c];
        s += v * As[c];
        d += v * Ad[c];
    }
    e2s[n] = s; e2d[n] = d;
}

// ---------------- layer-2 fused: ONLINE softmax-agg + bias + log_softmax -----
// R8: same two-deep (index,score) prefetch + skip-rescale branch as gat1.
__global__ __launch_bounds__(256) void gat2_logsm(
    const int* __restrict__ row_ptr, const int* __restrict__ eadj,
    const float* __restrict__ e2s, const float* __restrict__ e2d,
    const float* __restrict__ h2, const float* __restrict__ b2,
    float* __restrict__ out0) {
    int wave = threadIdx.x >> 6, lane = threadIdx.x & 63;
    int d = blockIdx.x * 4 + wave;
    if (d >= NN) return;
    int eslot = lane >> 3, c8 = lane & 7;
    float edv = e2d[d];
    int beg = row_ptr[d], end = row_ptr[d + 1];

    float mself = lrelu(e2s[d] + edv);
    float m = mself;
    float den = (eslot == 0) ? 1.f : 0.f;
    float acc[5];
    {
        const float* hp = h2 + (long)d * NCLASS + c8 * 5;
        #pragma unroll
        for (int k = 0; k < 5; k++) acc[k] = (eslot == 0) ? hp[k] : 0.f;
    }

    int sPre = (beg + eslot < end) ? eadj[beg + eslot] : 0;
    float elPre = lrelu(e2s[sPre] + edv);
    if (beg + eslot >= end) elPre = -1e30f;

    for (int i = beg; i < end; i += 8) {
        int idx = i + eslot;
        int s = sPre;
        float el = elPre;
        if (i + 8 < end) {                        // prefetch next group's chain
            int nidx = idx + 8;
            sPre = (nidx < end) ? eadj[nidx] : 0;
            float e1 = lrelu(e2s[sPre] + edv);
            elPre = (nidx < end) ? e1 : -1e30f;
        }
        float gm = el;
        gm = fmaxf(gm, __shfl_xor(gm, 8));
        gm = fmaxf(gm, __shfl_xor(gm, 16));
        gm = fmaxf(gm, __shfl_xor(gm, 32));
        if (__any(gm > m)) {                      // rescale only on max growth
            float mn = fmaxf(m, gm);
            float rsc = __expf(m - mn);
            m = mn;
            den *= rsc;
            #pragma unroll
            for (int k = 0; k < 5; k++) acc[k] *= rsc;
        }
        float wj = (idx < end) ? __expf(el - m) : 0.f;
        den += wj;
        if (idx < end) {
            const float* hp = h2 + (long)s * NCLASS + c8 * 5;
            #pragma unroll
            for (int k = 0; k < 5; k++) acc[k] += wj * hp[k];
        }
    }
    #pragma unroll
    for (int off = 8; off <= 32; off <<= 1) {
        den += __shfl_xor(den, off);
        #pragma unroll
        for (int k = 0; k < 5; k++) acc[k] += __shfl_xor(acc[k], off);
    }
    float inv = 1.f / den;
    float v[5];
    float mx = -1e30f;
    #pragma unroll
    for (int k = 0; k < 5; k++) {
        v[k] = acc[k] * inv + b2[c8 * 5 + k];
        mx = fmaxf(mx, v[k]);
    }
    #pragma unroll
    for (int off = 1; off <= 4; off <<= 1) mx = fmaxf(mx, __shfl_xor(mx, off));
    float sm = 0.f;
    #pragma unroll
    for (int k = 0; k < 5; k++) sm += __expf(v[k] - mx);
    #pragma unroll
    for (int off = 1; off <= 4; off <<= 1) sm += __shfl_xor(sm, off);
    float ls = mx + logf(sm);
    if (eslot == 0) {
        float* op = out0 + (long)d * NCLASS + c8 * 5;
        #pragma unroll
        for (int k = 0; k < 5; k++) op[k] = v[k] - ls;
    }
}

extern "C" void kernel_launch(void* const* d_in, const int* in_sizes, int n_in,
                              void* d_out, int out_size, void* d_ws, size_t ws_size,
                              hipStream_t stream) {
    const float* x   = (const float*)d_in[0];
    const int* ei    = (const int*)d_in[1];
    const float* W1  = (const float*)d_in[2];
    const float* as1 = (const float*)d_in[3];
    const float* ad1 = (const float*)d_in[4];
    const float* b1  = (const float*)d_in[5];
    const float* W2  = (const float*)d_in[6];
    const float* as2 = (const float*)d_in[7];
    const float* ad2 = (const float*)d_in[8];
    const float* b2  = (const float*)d_in[9];

    float* out0 = (float*)d_out;                   // [N,40] log_softmax
    float* h1o  = out0 + (long)NN * NCLASS;        // [N,256] h1 (fp32)

    // workspace layout
    unsigned short* hb = (unsigned short*)d_ws;               // N*F1 bf16 (51.2 MB)
    unsigned short* w1p = hb + (long)NN * F1;                 // 256*512 bf16 (packed)
    float* es1  = (float*)(w1p + F1 * NFEAT);                 // N*8
    float* ed1  = es1 + NN * HEADS;
    float* e2s  = ed1 + NN * HEADS;                           // N
    float* e2d  = e2s + NN;
    int* srcC   = (int*)(e2d + NN);                           // E
    int* dstC   = srcC + EE;                                  // E
    int* eadj   = dstC + EE;                                  // E
    int* deg    = eadj + EE;                                  // N
    int* row_ptr= deg + NN;                                   // N+1
    int* pos    = row_ptr + NN + 1;                           // N
    int* bsum   = pos + NN;                                   // NB1
    int* flag   = bsum + NB1;                                 // 1
    float* h2   = (float*)d_ws;                               // alias: N*40 (hb dead after gat1)

    hipMemsetAsync(flag, 0, 4, stream);
    hipMemsetAsync(deg, 0, (size_t)NN * 4, stream);

    // edge canonicalization + CSR build (canon fused with degree count)
    detect_i64<<<16, 256, 0, stream>>>(ei, flag);
    canon_edges<<<(EE + 255) / 256, 256, 0, stream>>>(ei, flag, srcC, dstC, deg);
    scan1<<<NB1, 256, 0, stream>>>(deg, bsum);
    scan2<<<1, 64, 0, stream>>>(bsum, row_ptr);
    scan3<<<NB1, 256, 0, stream>>>(deg, bsum, row_ptr, pos);
    fill_csr<<<(EE + 255) / 256, 256, 0, stream>>>(srcC, dstC, pos, eadj);

    // layer 1 (escore1 fused into gemm1 epilogue; 128-row M-tile, 8 waves)
    prep_w1<<<(NFEAT * F1 + 255) / 256, 256, 0, stream>>>(W1, w1p);
    gemm1_kernel<<<(NN + 127) / 128, 512, 0, stream>>>(x, w1p, as1, ad1, hb, es1, ed1);
    gat1_fused<<<(NN + 3) / 4, 256, 0, stream>>>(row_ptr, eadj, es1, ed1, hb, b1, h1o);

    // layer 2
    gemm2_kernel<<<(int)(((long)NN * 10 + 255) / 256), 256, 0, stream>>>(h1o, W2, h2);
    escore2_kernel<<<(NN + 255) / 256, 256, 0, stream>>>(h2, as2, ad2, e2s, e2d);
    gat2_logsm<<<(NN + 3) / 4, 256, 0, stream>>>(row_ptr, eadj, e2s, e2d, h2, b2, out0);
}